// Round 6
// baseline (556.325 us; speedup 1.0000x reference)
//
#include <hip/hip_runtime.h>

#define T_ 16
#define E_ 64
#define V_ 96
#define L_ 4

typedef unsigned int u32;
typedef unsigned short u16;
typedef __attribute__((ext_vector_type(8))) short bf16x8;
typedef __attribute__((ext_vector_type(4))) float f32x4;

#define MFMA(a, b, c) __builtin_amdgcn_mfma_f32_16x16x32_bf16(a, b, c, 0, 0, 0)

// ws layout (bf16/short elements): B-operand layout [n][k] per matrix
#define OFF_TQ 0
#define OFF_TK 16384
#define OFF_TV 32768
#define OFF_TWO 49152
#define OFF_TW1 65536
#define OFF_TW2 81920
#define OFF_TWOUT 98304
#define PREP_TOT 104448

__device__ __forceinline__ short f2b_rne(float f) {  // fp32 -> bf16 RNE (prep only)
  u32 u = __float_as_uint(f);
  u32 r = (u + 0x7fffu + ((u >> 16) & 1u)) >> 16;
  return (short)r;
}
__device__ __forceinline__ float b2f(short s) {
  return __uint_as_float(((u32)(u16)s) << 16);
}
// round-half-up bf16 pack: low short = bf16(a), high short = bf16(b). 3 VALU.
__device__ __forceinline__ u32 pack2_ru(float a, float b) {
  return __builtin_amdgcn_perm(__float_as_uint(a) + 0x8000u,
                               __float_as_uint(b) + 0x8000u, 0x03020706u);
}
// single-element round-half-up bf16 (same numerics as pack2_ru) for ds_write_b16
__device__ __forceinline__ short b16_ru(float f) {
  return (short)((__float_as_uint(f) + 0x8000u) >> 16);
}

// 16-lane-row reduction via DPP row_ror adds: pure VALU, zero LDS-pipe traffic.
template <int N>
__device__ __forceinline__ float ror_add(float x) {
  int y = __builtin_amdgcn_update_dpp(0, __float_as_int(x), 0x120 + N, 0xF, 0xF,
                                      true);
  return x + __int_as_float(y);
}
__device__ __forceinline__ float sum16(float x) {
  x = ror_add<8>(x);
  x = ror_add<4>(x);
  x = ror_add<2>(x);
  x = ror_add<1>(x);
  return x;
}

__global__ void __launch_bounds__(256) prep_weights(
    const float* __restrict__ Wq, const float* __restrict__ Wk,
    const float* __restrict__ Wv, const float* __restrict__ Wo,
    const float* __restrict__ W1, const float* __restrict__ W2,
    const float* __restrict__ Wout, short* __restrict__ wpo) {
  int id = blockIdx.x * 256 + threadIdx.x;
  if (id >= PREP_TOT) return;
  float v;
  if (id < OFF_TWO) {                       // TQ/TK/TV: n = h*16+kq, k = e
    int which = id >> 14;                   // 0=Q,1=K,2=V
    int r = id & 16383;
    int l = r >> 12, n = (r >> 6) & 63, e = r & 63;
    int h = n >> 4, kq = n & 15;
    const float* W = which == 0 ? Wq : (which == 1 ? Wk : Wv);
    v = W[((l * 4 + h) * 64 + e) * 16 + kq];
  } else if (id < OFF_TWOUT) {              // TWo/TW1/TW2: n = out col, k = e
    int id2 = id - OFF_TWO;
    int which = id2 >> 14;                  // 0=Wo,1=W1,2=W2
    int r = id2 & 16383;
    int l = r >> 12, n = (r >> 6) & 63, e = r & 63;
    const float* W = which == 0 ? Wo : (which == 1 ? W1 : W2);
    v = W[(l * 64 + e) * 64 + n];
  } else {                                  // TWout: n = vocab col, k = e
    int r = id - OFF_TWOUT;
    int n = r >> 6, e = r & 63;
    v = Wout[e * 96 + n];
  }
  wpo[id] = f2b_rne(v);
}

// LayerNorm over 64 cols held as 4 n-regs x 16 lanes (same qq group), rows r.
__device__ __forceinline__ void ln16(float vals[4][4]) {
#pragma unroll
  for (int r = 0; r < 4; ++r) {
    float s = vals[0][r] + vals[1][r] + vals[2][r] + vals[3][r];
    s = sum16(s);
    float mean = s * 0.015625f;
    float vv = 0.f;
#pragma unroll
    for (int n = 0; n < 4; ++n) { float d = vals[n][r] - mean; vv = fmaf(d, d, vv); }
    vv = sum16(vv);
    float rst = rsqrtf(vv * 0.015625f + 1e-5f);
#pragma unroll
    for (int n = 0; n < 4; ++n) vals[n][r] = (vals[n][r] - mean) * rst;
  }
}

// 256 threads = 4 waves; wave w handles TWO sequences (blockIdx.x*8 + w*2 + s).
// Unified-RF model (fits rounds 1-5): VGPR_Count excludes AGPRs; true per-wave
// allocation is ~124-128 regs -> occupancy pinned at 4 waves/EU regardless of
// LDS. So latency hiding comes from 2 independent per-seq chains per wave.
// Round-4/5 spilled (~440 MB scratch) because 2-seq peak pressure > 128-reg
// budget. This version cuts peak pressure: per-seq LN/FF/epilogue phases
// (vals/A-frags not doubled; weights re-read for s=1 = L1 hits) and split
// Q-pass/K-pass in phase 2a (half the live weight frags).
// No __syncthreads: LDS wave-private, DS pipe in-order per wave. Per seq: 2
// arenas, ping-pong per layer; cols 64..71 zero (A-frag upper-K pad).
__global__ void __launch_bounds__(256, 4) bert_mfma(
    const int* __restrict__ data,
    const float* __restrict__ tok_emb, const float* __restrict__ pos_emb,
    const float* __restrict__ bo, const float* __restrict__ ln1g,
    const float* __restrict__ ln1b, const float* __restrict__ ln2g,
    const float* __restrict__ ln2b, const float* __restrict__ b1,
    const float* __restrict__ b2, const float* __restrict__ bout,
    const short* __restrict__ wp, float* __restrict__ out) {
  __shared__ __align__(16) short R[4][2][2][16][72];  // [wave][seq][arena]

  const int w = threadIdx.x >> 6;
  const int lane = threadIdx.x & 63;
  const int m = lane & 15;   // A-row t / B-row / C-col
  const int qq = lane >> 4;  // k-chunk for frags; C rows qq*4+r
  const int seq0 = blockIdx.x * 8 + w * 2;

  short(*cur[2])[72] = {R[w][0][0], R[w][1][0]};
  short(*oth[2])[72] = {R[w][0][1], R[w][1][1]};

  // zero cols 64..71 of all 4 arenas: A-frag upper-K lanes (qq>=2) read here -> 0
  if (lane < 16) {
#pragma unroll
    for (int s = 0; s < 2; ++s) {
      *(float4*)&R[w][s][0][lane][64] = make_float4(0.f, 0.f, 0.f, 0.f);
      *(float4*)&R[w][s][1][lane][64] = make_float4(0.f, 0.f, 0.f, 0.f);
    }
  }

  // ---- embedding: x = tok_emb[data] + pos_emb -> cur[s] bf16 [t][e] ----
#pragma unroll
  for (int s = 0; s < 2; ++s) {
    const int t = lane >> 2;
    const int c0 = (lane & 3) * 16;
    const int tok = data[(seq0 + s) * T_ + t];
    const float4* tp = (const float4*)(tok_emb + tok * E_ + c0);
    const float4* pp = (const float4*)(pos_emb + t * E_ + c0);
    u32 buf[8];
#pragma unroll
    for (int q = 0; q < 4; ++q) {
      float4 a = tp[q], b = pp[q];
      buf[q * 2 + 0] = pack2_ru(a.x + b.x, a.y + b.y);
      buf[q * 2 + 1] = pack2_ru(a.z + b.z, a.w + b.w);
    }
    ((bf16x8*)&cur[s][t][c0])[0] = ((bf16x8*)buf)[0];
    *(bf16x8*)&cur[s][t][c0 + 8] = ((bf16x8*)(buf + 4))[0];
  }

  // residual stream, C-layout regs: xres[s][n][r] = x_s[qq*4+r][n*16+m]
  float xres[2][4][4];
#pragma unroll
  for (int s = 0; s < 2; ++s)
#pragma unroll
    for (int n = 0; n < 4; ++n)
#pragma unroll
      for (int r = 0; r < 4; ++r) xres[s][n][r] = b2f(cur[s][qq * 4 + r][n * 16 + m]);

  const f32x4 z4 = {0.f, 0.f, 0.f, 0.f};
  const int hselA = (qq < 2) ? 16 : 0;               // head stride for A-frag
  const int aoffA = (qq < 2) ? ((qq & 1) * 8) : 64;  // qq>=2 -> zero cols
  const int boff = (qq & 1) * 8;  // B-frag k>=16 multiplied by A zeros

#pragma unroll 1
  for (int l = 0; l < L_; ++l) {
    const short* TQ = wp + OFF_TQ + l * 4096;
    const short* TK = wp + OFF_TK + l * 4096;
    const short* TV = wp + OFF_TV + l * 4096;
    const short* TWO = wp + OFF_TWO + l * 4096;
    const short* TW1 = wp + OFF_TW1 + l * 4096;
    const short* TW2 = wp + OFF_TW2 + l * 4096;

    // phase 1: x A-frags to regs (x in LDS dead afterwards)
    bf16x8 ax0[2], ax1[2];
#pragma unroll
    for (int s = 0; s < 2; ++s) {
      ax0[s] = *(const bf16x8*)&cur[s][m][qq * 8];
      ax1[s] = *(const bf16x8*)&cur[s][m][32 + qq * 8];
    }

    // phase 2a-Q: q -> cur (over x). Separate Q and K passes: half the live
    // weight fragments at peak.
#pragma unroll
    for (int h = 0; h < 4; ++h) {
      const int bn = (h * 16 + m) * 64 + qq * 8;
      bf16x8 bq0 = *(const bf16x8*)(TQ + bn), bq1 = *(const bf16x8*)(TQ + bn + 32);
#pragma unroll
      for (int s = 0; s < 2; ++s) {
        f32x4 qa = MFMA(ax0[s], bq0, z4); qa = MFMA(ax1[s], bq1, qa);
#pragma unroll
        for (int r = 0; r < 4; ++r) cur[s][qq * 4 + r][h * 16 + m] = b16_ru(qa[r]);
      }
    }
    // phase 2a-K: k -> oth
#pragma unroll
    for (int h = 0; h < 4; ++h) {
      const int bn = (h * 16 + m) * 64 + qq * 8;
      bf16x8 bk0 = *(const bf16x8*)(TK + bn), bk1 = *(const bf16x8*)(TK + bn + 32);
#pragma unroll
      for (int s = 0; s < 2; ++s) {
        f32x4 ka = MFMA(ax0[s], bk0, z4); ka = MFMA(ax1[s], bk1, ka);
#pragma unroll
        for (int r = 0; r < 4; ++r) oth[s][qq * 4 + r][h * 16 + m] = b16_ru(ka[r]);
      }
    }

    // phase 3+4 fused per head: S_h = q k^T, p = exp(S/4) -> cur (over q[h];
    // reads of q[h]/k[h] precede the p[h] write in-order on the DS pipe)
#pragma unroll
    for (int h = 0; h < 4; ++h) {
#pragma unroll
      for (int s = 0; s < 2; ++s) {
        bf16x8 aq = *(const bf16x8*)&cur[s][m][h * hselA + aoffA];
        bf16x8 bk = *(const bf16x8*)&oth[s][m][h * 16 + boff];
        f32x4 sc = MFMA(aq, bk, z4);
#pragma unroll
        for (int r = 0; r < 4; ++r) {
          float e = __expf(sc[r] * 0.25f);
          cur[s][qq * 4 + r][h * 16 + m] = b16_ru(e);
        }
      }
    }

    // phase 2b: V -> vT into oth (over k; all k reads done above)
#pragma unroll
    for (int h = 0; h < 4; ++h) {
      const int bn = (h * 16 + m) * 64 + qq * 8;
      bf16x8 bv0 = *(const bf16x8*)(TV + bn), bv1 = *(const bf16x8*)(TV + bn + 32);
#pragma unroll
      for (int s = 0; s < 2; ++s) {
        f32x4 va = MFMA(ax0[s], bv0, z4); va = MFMA(ax1[s], bv1, va);
        // vT[kd][h*16+t]: 4 consecutive t in-lane -> one b64
        *(uint2*)&oth[s][m][h * 16 + qq * 4] =
            make_uint2(pack2_ru(va[0], va[1]), pack2_ru(va[2], va[3]));
      }
    }

    // phase 5+6 fused per head: O_h = p V (rowsum via ones-B MFMA), normalize,
    // concat -> cur (over p[h]; p[h] reads precede the o[h] write in-order)
    {
      const short s1b = (short)0x3F80;
      const bf16x8 ones8 = {s1b, s1b, s1b, s1b, s1b, s1b, s1b, s1b};
#pragma unroll
      for (int h = 0; h < 4; ++h) {
#pragma unroll
        for (int s = 0; s < 2; ++s) {
          bf16x8 ap = *(const bf16x8*)&cur[s][m][h * hselA + aoffA];
          bf16x8 bv = *(const bf16x8*)&oth[s][m][h * 16 + boff];
          f32x4 ot = MFMA(ap, bv, z4);
          f32x4 rs = MFMA(ap, ones8, z4);
#pragma unroll
          for (int r = 0; r < 4; ++r) {
            float o = ot[r] * __builtin_amdgcn_rcpf(rs[r]);
            cur[s][qq * 4 + r][h * 16 + m] = b16_ru(o);
          }
        }
      }
    }

    // phase 7 (PER-SEQ): x1 = LN1(x + o@Wo + bo) -> oth (over vT), xres.
    // Weights re-read per seq (L1 hits) to halve live vals/A-frags.
#pragma unroll
    for (int s = 0; s < 2; ++s) {
      bf16x8 ao0 = *(const bf16x8*)&cur[s][m][qq * 8];
      bf16x8 ao1 = *(const bf16x8*)&cur[s][m][32 + qq * 8];
      float vals[4][4];
#pragma unroll
      for (int n = 0; n < 4; ++n) {
        const int bn = (n * 16 + m) * 64 + qq * 8;
        bf16x8 w0 = *(const bf16x8*)(TWO + bn), w1 = *(const bf16x8*)(TWO + bn + 32);
        f32x4 d = MFMA(ao0, w0, z4); d = MFMA(ao1, w1, d);
        float bcol = bo[l * E_ + n * 16 + m];
#pragma unroll
        for (int r = 0; r < 4; ++r) vals[n][r] = xres[s][n][r] + d[r] + bcol;
      }
      ln16(vals);
#pragma unroll
      for (int n = 0; n < 4; ++n) {
        float g = ln1g[l * E_ + n * 16 + m];
        float bb = ln1b[l * E_ + n * 16 + m];
#pragma unroll
        for (int r = 0; r < 4; ++r) {
          float xv = fmaf(vals[n][r], g, bb);
          xres[s][n][r] = xv;
          oth[s][qq * 4 + r][n * 16 + m] = b16_ru(xv);
        }
      }
    }

    // phase 8 (PER-SEQ): h1 = relu(x1@W1 + b1) -> cur (over ob)
#pragma unroll
    for (int s = 0; s < 2; ++s) {
      bf16x8 a10 = *(const bf16x8*)&oth[s][m][qq * 8];
      bf16x8 a11 = *(const bf16x8*)&oth[s][m][32 + qq * 8];
#pragma unroll
      for (int n = 0; n < 4; ++n) {
        const int bn = (n * 16 + m) * 64 + qq * 8;
        bf16x8 w0 = *(const bf16x8*)(TW1 + bn), w1 = *(const bf16x8*)(TW1 + bn + 32);
        f32x4 acc = MFMA(a10, w0, z4); acc = MFMA(a11, w1, acc);
        float bcol = b1[l * E_ + n * 16 + m];
#pragma unroll
        for (int r = 0; r < 4; ++r) {
          float hv = fmaxf(acc[r] + bcol, 0.f);
          cur[s][qq * 4 + r][n * 16 + m] = b16_ru(hv);
        }
      }
    }

    // phase 9 (PER-SEQ): x = LN2(x1 + h1@W2 + b2) -> oth (over x1)
#pragma unroll
    for (int s = 0; s < 2; ++s) {
      bf16x8 a20 = *(const bf16x8*)&cur[s][m][qq * 8];
      bf16x8 a21 = *(const bf16x8*)&cur[s][m][32 + qq * 8];
      float vals[4][4];
#pragma unroll
      for (int n = 0; n < 4; ++n) {
        const int bn = (n * 16 + m) * 64 + qq * 8;
        bf16x8 w0 = *(const bf16x8*)(TW2 + bn), w1 = *(const bf16x8*)(TW2 + bn + 32);
        f32x4 d = MFMA(a20, w0, z4); d = MFMA(a21, w1, d);
        float bcol = b2[l * E_ + n * 16 + m];
#pragma unroll
        for (int r = 0; r < 4; ++r) vals[n][r] = xres[s][n][r] + d[r] + bcol;
      }
      ln16(vals);
#pragma unroll
      for (int n = 0; n < 4; ++n) {
        float g = ln2g[l * E_ + n * 16 + m];
        float bb = ln2b[l * E_ + n * 16 + m];
#pragma unroll
        for (int r = 0; r < 4; ++r) {
          float xv = fmaf(vals[n][r], g, bb);
          xres[s][n][r] = xv;
          oth[s][qq * 4 + r][n * 16 + m] = b16_ru(xv);
        }
      }
    }

    // ping-pong arenas: next layer's x is in oth
#pragma unroll
    for (int s = 0; s < 2; ++s) {
      short(*tmp)[72] = cur[s]; cur[s] = oth[s]; oth[s] = tmp;
    }
  }

  // epilogue (PER-SEQ): logits = x @ Wout + bout, fp32 coalesced stores
  {
    const short* TWOUT = wp + OFF_TWOUT;
#pragma unroll
    for (int s = 0; s < 2; ++s) {
      bf16x8 af0 = *(const bf16x8*)&cur[s][m][qq * 8];
      bf16x8 af1 = *(const bf16x8*)&cur[s][m][32 + qq * 8];
#pragma unroll
      for (int n = 0; n < 6; ++n) {
        const int bn = (n * 16 + m) * 64 + qq * 8;
        bf16x8 w0 = *(const bf16x8*)(TWOUT + bn), w1 = *(const bf16x8*)(TWOUT + bn + 32);
        f32x4 acc = MFMA(af0, w0, z4); acc = MFMA(af1, w1, acc);
        float bcol = bout[n * 16 + m];
#pragma unroll
        for (int r = 0; r < 4; ++r)
          out[((seq0 + s) * T_ + qq * 4 + r) * V_ + n * 16 + m] = acc[r] + bcol;
      }
    }
  }
}

extern "C" void kernel_launch(void* const* d_in, const int* in_sizes, int n_in,
                              void* d_out, int out_size, void* d_ws, size_t ws_size,
                              hipStream_t stream) {
  const int*   data    = (const int*)d_in[0];
  const float* tok_emb = (const float*)d_in[1];
  const float* pos_emb = (const float*)d_in[2];
  const float* Wq      = (const float*)d_in[3];
  const float* Wk      = (const float*)d_in[4];
  const float* Wv      = (const float*)d_in[5];
  const float* Wo      = (const float*)d_in[6];
  const float* bo      = (const float*)d_in[7];
  const float* ln1g    = (const float*)d_in[8];
  const float* ln1b    = (const float*)d_in[9];
  const float* ln2g    = (const float*)d_in[10];
  const float* ln2b    = (const float*)d_in[11];
  const float* W1      = (const float*)d_in[12];
  const float* b1      = (const float*)d_in[13];
  const float* W2      = (const float*)d_in[14];
  const float* b2      = (const float*)d_in[15];
  const float* Wout    = (const float*)d_in[16];
  const float* bout    = (const float*)d_in[17];
  float* out = (float*)d_out;
  short* wp = (short*)d_ws;  // 104448*2 = 208896 B of workspace

  prep_weights<<<(PREP_TOT + 255) / 256, 256, 0, stream>>>(
      Wq, Wk, Wv, Wo, W1, W2, Wout, wp);

  const int B = in_sizes[0] / T_;  // 16384 sequences, 8 per block (2 per wave)
  bert_mfma<<<B / 8, 256, 0, stream>>>(data, tok_emb, pos_emb, bo, ln1g, ln1b,
                                       ln2g, ln2b, b1, b2, bout, wp, out);
}

// Round 7
// 478.088 us; speedup vs baseline: 1.1636x; 1.1636x over previous
//
#include <hip/hip_runtime.h>

#define T_ 16
#define E_ 64
#define V_ 96
#define L_ 4

typedef unsigned int u32;
typedef unsigned short u16;
typedef __attribute__((ext_vector_type(8))) short bf16x8;
typedef __attribute__((ext_vector_type(4))) float f32x4;

#define MFMA(a, b, c) __builtin_amdgcn_mfma_f32_16x16x32_bf16(a, b, c, 0, 0, 0)

// ws layout (bf16/short elements): B-operand layout [n][k] per matrix
#define OFF_TQ 0
#define OFF_TK 16384
#define OFF_TV 32768
#define OFF_TWO 49152
#define OFF_TW1 65536
#define OFF_TW2 81920
#define OFF_TWOUT 98304
#define PREP_TOT 104448

__device__ __forceinline__ short f2b_rne(float f) {  // fp32 -> bf16 RNE (prep only)
  u32 u = __float_as_uint(f);
  u32 r = (u + 0x7fffu + ((u >> 16) & 1u)) >> 16;
  return (short)r;
}
__device__ __forceinline__ float b2f(short s) {
  return __uint_as_float(((u32)(u16)s) << 16);
}
// round-half-up bf16 pack: low short = bf16(a), high short = bf16(b). 3 VALU.
__device__ __forceinline__ u32 pack2_ru(float a, float b) {
  return __builtin_amdgcn_perm(__float_as_uint(a) + 0x8000u,
                               __float_as_uint(b) + 0x8000u, 0x03020706u);
}
// single-element round-half-up bf16 (same numerics as pack2_ru) for ds_write_b16
__device__ __forceinline__ short b16_ru(float f) {
  return (short)((__float_as_uint(f) + 0x8000u) >> 16);
}

// 16-lane-row reduction via DPP row_ror adds: pure VALU, zero LDS-pipe traffic.
template <int N>
__device__ __forceinline__ float ror_add(float x) {
  int y = __builtin_amdgcn_update_dpp(0, __float_as_int(x), 0x120 + N, 0xF, 0xF,
                                      true);
  return x + __int_as_float(y);
}
__device__ __forceinline__ float sum16(float x) {
  x = ror_add<8>(x);
  x = ror_add<4>(x);
  x = ror_add<2>(x);
  x = ror_add<1>(x);
  return x;
}

__global__ void __launch_bounds__(256) prep_weights(
    const float* __restrict__ Wq, const float* __restrict__ Wk,
    const float* __restrict__ Wv, const float* __restrict__ Wo,
    const float* __restrict__ W1, const float* __restrict__ W2,
    const float* __restrict__ Wout, short* __restrict__ wpo) {
  int id = blockIdx.x * 256 + threadIdx.x;
  if (id >= PREP_TOT) return;
  float v;
  if (id < OFF_TWO) {                       // TQ/TK/TV: n = h*16+kq, k = e
    int which = id >> 14;                   // 0=Q,1=K,2=V
    int r = id & 16383;
    int l = r >> 12, n = (r >> 6) & 63, e = r & 63;
    int h = n >> 4, kq = n & 15;
    const float* W = which == 0 ? Wq : (which == 1 ? Wk : Wv);
    v = W[((l * 4 + h) * 64 + e) * 16 + kq];
  } else if (id < OFF_TWOUT) {              // TWo/TW1/TW2: n = out col, k = e
    int id2 = id - OFF_TWO;
    int which = id2 >> 14;                  // 0=Wo,1=W1,2=W2
    int r = id2 & 16383;
    int l = r >> 12, n = (r >> 6) & 63, e = r & 63;
    const float* W = which == 0 ? Wo : (which == 1 ? W1 : W2);
    v = W[(l * 64 + e) * 64 + n];
  } else {                                  // TWout: n = vocab col, k = e
    int r = id - OFF_TWOUT;
    int n = r >> 6, e = r & 63;
    v = Wout[e * 96 + n];
  }
  wpo[id] = f2b_rne(v);
}

// LayerNorm over 64 cols held as 4 n-regs x 16 lanes (same qq group), rows r.
__device__ __forceinline__ void ln16(float vals[4][4]) {
#pragma unroll
  for (int r = 0; r < 4; ++r) {
    float s = vals[0][r] + vals[1][r] + vals[2][r] + vals[3][r];
    s = sum16(s);
    float mean = s * 0.015625f;
    float vv = 0.f;
#pragma unroll
    for (int n = 0; n < 4; ++n) { float d = vals[n][r] - mean; vv = fmaf(d, d, vv); }
    vv = sum16(vv);
    float rst = rsqrtf(vv * 0.015625f + 1e-5f);
#pragma unroll
    for (int n = 0; n < 4; ++n) vals[n][r] = (vals[n][r] - mean) * rst;
  }
}

// 256 threads = 4 waves; wave w handles TWO sequences (blockIdx.x*8 + w*2 + s).
// Occupancy is pinned at 4 waves/SIMD by the unified VGPR+AGPR allocation
// (~128 regs/wave; rocprof VGPR_Count=64 shows arch half only). Latency hiding
// therefore comes from 2 independent per-seq chains per wave, interleaved at
// the instruction level inside EVERY phase (round 6 proved per-seq phases cost
// ~90 µs). Round 4's spill (~440 MB scratch) is attacked by cutting peak
// pressure WITHOUT serializing: (a) vals[2][4][4] eliminated — residual+MFMA
// accumulate in place in xres, ln16 runs on xres directly (-32 live regs at
// the phase-7/9 peak); (b) phase 2a split into Q-pass/K-pass (-8 regs at peak,
// still s-interleaved). No __syncthreads: LDS wave-private, DS pipe in-order.
// Per seq: 2 arenas, ping-pong per layer; cols 64..71 zero (A-frag pad).
__global__ void __launch_bounds__(256, 4) bert_mfma(
    const int* __restrict__ data,
    const float* __restrict__ tok_emb, const float* __restrict__ pos_emb,
    const float* __restrict__ bo, const float* __restrict__ ln1g,
    const float* __restrict__ ln1b, const float* __restrict__ ln2g,
    const float* __restrict__ ln2b, const float* __restrict__ b1,
    const float* __restrict__ b2, const float* __restrict__ bout,
    const short* __restrict__ wp, float* __restrict__ out) {
  __shared__ __align__(16) short R[4][2][2][16][72];  // [wave][seq][arena]

  const int w = threadIdx.x >> 6;
  const int lane = threadIdx.x & 63;
  const int m = lane & 15;   // A-row t / B-row / C-col
  const int qq = lane >> 4;  // k-chunk for frags; C rows qq*4+r
  const int seq0 = blockIdx.x * 8 + w * 2;

  short(*cur[2])[72] = {R[w][0][0], R[w][1][0]};
  short(*oth[2])[72] = {R[w][0][1], R[w][1][1]};

  // zero cols 64..71 of all 4 arenas: A-frag upper-K lanes (qq>=2) read here -> 0
  if (lane < 16) {
#pragma unroll
    for (int s = 0; s < 2; ++s) {
      *(float4*)&R[w][s][0][lane][64] = make_float4(0.f, 0.f, 0.f, 0.f);
      *(float4*)&R[w][s][1][lane][64] = make_float4(0.f, 0.f, 0.f, 0.f);
    }
  }

  // ---- embedding: x = tok_emb[data] + pos_emb -> cur[s] bf16 [t][e] ----
#pragma unroll
  for (int s = 0; s < 2; ++s) {
    const int t = lane >> 2;
    const int c0 = (lane & 3) * 16;
    const int tok = data[(seq0 + s) * T_ + t];
    const float4* tp = (const float4*)(tok_emb + tok * E_ + c0);
    const float4* pp = (const float4*)(pos_emb + t * E_ + c0);
    u32 buf[8];
#pragma unroll
    for (int q = 0; q < 4; ++q) {
      float4 a = tp[q], b = pp[q];
      buf[q * 2 + 0] = pack2_ru(a.x + b.x, a.y + b.y);
      buf[q * 2 + 1] = pack2_ru(a.z + b.z, a.w + b.w);
    }
    ((bf16x8*)&cur[s][t][c0])[0] = ((bf16x8*)buf)[0];
    *(bf16x8*)&cur[s][t][c0 + 8] = ((bf16x8*)(buf + 4))[0];
  }

  // residual stream, C-layout regs: xres[s][n][r] = x_s[qq*4+r][n*16+m]
  float xres[2][4][4];
#pragma unroll
  for (int s = 0; s < 2; ++s)
#pragma unroll
    for (int n = 0; n < 4; ++n)
#pragma unroll
      for (int r = 0; r < 4; ++r) xres[s][n][r] = b2f(cur[s][qq * 4 + r][n * 16 + m]);

  const f32x4 z4 = {0.f, 0.f, 0.f, 0.f};
  const int hselA = (qq < 2) ? 16 : 0;               // head stride for A-frag
  const int aoffA = (qq < 2) ? ((qq & 1) * 8) : 64;  // qq>=2 -> zero cols
  const int boff = (qq & 1) * 8;  // B-frag k>=16 multiplied by A zeros

#pragma unroll 1
  for (int l = 0; l < L_; ++l) {
    const short* TQ = wp + OFF_TQ + l * 4096;
    const short* TK = wp + OFF_TK + l * 4096;
    const short* TV = wp + OFF_TV + l * 4096;
    const short* TWO = wp + OFF_TWO + l * 4096;
    const short* TW1 = wp + OFF_TW1 + l * 4096;
    const short* TW2 = wp + OFF_TW2 + l * 4096;

    // phase 1: x A-frags to regs (x in LDS dead afterwards)
    bf16x8 ax0[2], ax1[2];
#pragma unroll
    for (int s = 0; s < 2; ++s) {
      ax0[s] = *(const bf16x8*)&cur[s][m][qq * 8];
      ax1[s] = *(const bf16x8*)&cur[s][m][32 + qq * 8];
    }

    // phase 2a-Q: q -> cur (over x); separate Q/K passes halve live weight
    // frags at peak, s-interleave preserved.
#pragma unroll
    for (int h = 0; h < 4; ++h) {
      const int bn = (h * 16 + m) * 64 + qq * 8;
      bf16x8 bq0 = *(const bf16x8*)(TQ + bn), bq1 = *(const bf16x8*)(TQ + bn + 32);
#pragma unroll
      for (int s = 0; s < 2; ++s) {
        f32x4 qa = MFMA(ax0[s], bq0, z4); qa = MFMA(ax1[s], bq1, qa);
#pragma unroll
        for (int r = 0; r < 4; ++r) cur[s][qq * 4 + r][h * 16 + m] = b16_ru(qa[r]);
      }
    }
    // phase 2a-K: k -> oth
#pragma unroll
    for (int h = 0; h < 4; ++h) {
      const int bn = (h * 16 + m) * 64 + qq * 8;
      bf16x8 bk0 = *(const bf16x8*)(TK + bn), bk1 = *(const bf16x8*)(TK + bn + 32);
#pragma unroll
      for (int s = 0; s < 2; ++s) {
        f32x4 ka = MFMA(ax0[s], bk0, z4); ka = MFMA(ax1[s], bk1, ka);
#pragma unroll
        for (int r = 0; r < 4; ++r) oth[s][qq * 4 + r][h * 16 + m] = b16_ru(ka[r]);
      }
    }

    // phase 3+4 fused per head: S_h = q k^T, p = exp(S/4) -> cur (over q[h];
    // reads of q[h]/k[h] precede the p[h] write in-order on the DS pipe)
#pragma unroll
    for (int h = 0; h < 4; ++h) {
#pragma unroll
      for (int s = 0; s < 2; ++s) {
        bf16x8 aq = *(const bf16x8*)&cur[s][m][h * hselA + aoffA];
        bf16x8 bk = *(const bf16x8*)&oth[s][m][h * 16 + boff];
        f32x4 sc = MFMA(aq, bk, z4);
#pragma unroll
        for (int r = 0; r < 4; ++r) {
          float e = __expf(sc[r] * 0.25f);
          cur[s][qq * 4 + r][h * 16 + m] = b16_ru(e);
        }
      }
    }

    // phase 2b: V -> vT into oth (over k; all k reads done above)
#pragma unroll
    for (int h = 0; h < 4; ++h) {
      const int bn = (h * 16 + m) * 64 + qq * 8;
      bf16x8 bv0 = *(const bf16x8*)(TV + bn), bv1 = *(const bf16x8*)(TV + bn + 32);
#pragma unroll
      for (int s = 0; s < 2; ++s) {
        f32x4 va = MFMA(ax0[s], bv0, z4); va = MFMA(ax1[s], bv1, va);
        // vT[kd][h*16+t]: 4 consecutive t in-lane -> one b64
        *(uint2*)&oth[s][m][h * 16 + qq * 4] =
            make_uint2(pack2_ru(va[0], va[1]), pack2_ru(va[2], va[3]));
      }
    }

    // phase 5+6 fused per head: O_h = p V (rowsum via ones-B MFMA), normalize,
    // concat -> cur (over p[h]; p[h] reads precede the o[h] write in-order)
    {
      const short s1b = (short)0x3F80;
      const bf16x8 ones8 = {s1b, s1b, s1b, s1b, s1b, s1b, s1b, s1b};
#pragma unroll
      for (int h = 0; h < 4; ++h) {
#pragma unroll
        for (int s = 0; s < 2; ++s) {
          bf16x8 ap = *(const bf16x8*)&cur[s][m][h * hselA + aoffA];
          bf16x8 bv = *(const bf16x8*)&oth[s][m][h * 16 + boff];
          f32x4 ot = MFMA(ap, bv, z4);
          f32x4 rs = MFMA(ap, ones8, z4);
#pragma unroll
          for (int r = 0; r < 4; ++r) {
            float o = ot[r] * __builtin_amdgcn_rcpf(rs[r]);
            cur[s][qq * 4 + r][h * 16 + m] = b16_ru(o);
          }
        }
      }
    }

    // phase 7: x1 = LN1(x + o@Wo + bo) -> oth (over vT), xres IN PLACE
    // (no vals[] copy: -32 live regs at peak; s-interleave preserved)
    {
      bf16x8 ao0[2], ao1[2];
#pragma unroll
      for (int s = 0; s < 2; ++s) {
        ao0[s] = *(const bf16x8*)&cur[s][m][qq * 8];
        ao1[s] = *(const bf16x8*)&cur[s][m][32 + qq * 8];
      }
#pragma unroll
      for (int n = 0; n < 4; ++n) {
        const int bn = (n * 16 + m) * 64 + qq * 8;
        bf16x8 w0 = *(const bf16x8*)(TWO + bn), w1 = *(const bf16x8*)(TWO + bn + 32);
        float bcol = bo[l * E_ + n * 16 + m];
#pragma unroll
        for (int s = 0; s < 2; ++s) {
          f32x4 d = MFMA(ao0[s], w0, z4); d = MFMA(ao1[s], w1, d);
#pragma unroll
          for (int r = 0; r < 4; ++r) xres[s][n][r] += d[r] + bcol;
        }
      }
#pragma unroll
      for (int s = 0; s < 2; ++s) ln16(xres[s]);
#pragma unroll
      for (int n = 0; n < 4; ++n) {
        float g = ln1g[l * E_ + n * 16 + m];
        float bb = ln1b[l * E_ + n * 16 + m];
#pragma unroll
        for (int s = 0; s < 2; ++s)
#pragma unroll
          for (int r = 0; r < 4; ++r) {
            float xv = fmaf(xres[s][n][r], g, bb);
            xres[s][n][r] = xv;
            oth[s][qq * 4 + r][n * 16 + m] = b16_ru(xv);
          }
      }
    }

    // phase 8: h1 = relu(x1@W1 + b1) -> cur (over ob)
    {
      bf16x8 a10[2], a11[2];
#pragma unroll
      for (int s = 0; s < 2; ++s) {
        a10[s] = *(const bf16x8*)&oth[s][m][qq * 8];
        a11[s] = *(const bf16x8*)&oth[s][m][32 + qq * 8];
      }
#pragma unroll
      for (int n = 0; n < 4; ++n) {
        const int bn = (n * 16 + m) * 64 + qq * 8;
        bf16x8 w0 = *(const bf16x8*)(TW1 + bn), w1 = *(const bf16x8*)(TW1 + bn + 32);
        float bcol = b1[l * E_ + n * 16 + m];
#pragma unroll
        for (int s = 0; s < 2; ++s) {
          f32x4 acc = MFMA(a10[s], w0, z4); acc = MFMA(a11[s], w1, acc);
#pragma unroll
          for (int r = 0; r < 4; ++r) {
            float hv = fmaxf(acc[r] + bcol, 0.f);
            cur[s][qq * 4 + r][n * 16 + m] = b16_ru(hv);
          }
        }
      }
    }

    // phase 9: x = LN2(x1 + h1@W2 + b2) -> oth (over x1), xres IN PLACE
    {
      bf16x8 a20[2], a21[2];
#pragma unroll
      for (int s = 0; s < 2; ++s) {
        a20[s] = *(const bf16x8*)&cur[s][m][qq * 8];
        a21[s] = *(const bf16x8*)&cur[s][m][32 + qq * 8];
      }
#pragma unroll
      for (int n = 0; n < 4; ++n) {
        const int bn = (n * 16 + m) * 64 + qq * 8;
        bf16x8 w0 = *(const bf16x8*)(TW2 + bn), w1 = *(const bf16x8*)(TW2 + bn + 32);
        float bcol = b2[l * E_ + n * 16 + m];
#pragma unroll
        for (int s = 0; s < 2; ++s) {
          f32x4 d = MFMA(a20[s], w0, z4); d = MFMA(a21[s], w1, d);
#pragma unroll
          for (int r = 0; r < 4; ++r) xres[s][n][r] += d[r] + bcol;
        }
      }
#pragma unroll
      for (int s = 0; s < 2; ++s) ln16(xres[s]);
#pragma unroll
      for (int n = 0; n < 4; ++n) {
        float g = ln2g[l * E_ + n * 16 + m];
        float bb = ln2b[l * E_ + n * 16 + m];
#pragma unroll
        for (int s = 0; s < 2; ++s)
#pragma unroll
          for (int r = 0; r < 4; ++r) {
            float xv = fmaf(xres[s][n][r], g, bb);
            xres[s][n][r] = xv;
            oth[s][qq * 4 + r][n * 16 + m] = b16_ru(xv);
          }
      }
    }

    // ping-pong arenas: next layer's x is in oth
#pragma unroll
    for (int s = 0; s < 2; ++s) {
      short(*tmp)[72] = cur[s]; cur[s] = oth[s]; oth[s] = tmp;
    }
  }

  // epilogue: logits = x @ Wout + bout (6 n-tiles), fp32 coalesced stores
  // (xres dead here; interleaved pressure is low)
  {
    bf16x8 af0[2], af1[2];
#pragma unroll
    for (int s = 0; s < 2; ++s) {
      af0[s] = *(const bf16x8*)&cur[s][m][qq * 8];
      af1[s] = *(const bf16x8*)&cur[s][m][32 + qq * 8];
    }
    const short* TWOUT = wp + OFF_TWOUT;
#pragma unroll
    for (int n = 0; n < 6; ++n) {
      const int bn = (n * 16 + m) * 64 + qq * 8;
      bf16x8 w0 = *(const bf16x8*)(TWOUT + bn), w1 = *(const bf16x8*)(TWOUT + bn + 32);
      float bcol = bout[n * 16 + m];
#pragma unroll
      for (int s = 0; s < 2; ++s) {
        f32x4 acc = MFMA(af0[s], w0, z4); acc = MFMA(af1[s], w1, acc);
#pragma unroll
        for (int r = 0; r < 4; ++r)
          out[((seq0 + s) * T_ + qq * 4 + r) * V_ + n * 16 + m] = acc[r] + bcol;
      }
    }
  }
}

extern "C" void kernel_launch(void* const* d_in, const int* in_sizes, int n_in,
                              void* d_out, int out_size, void* d_ws, size_t ws_size,
                              hipStream_t stream) {
  const int*   data    = (const int*)d_in[0];
  const float* tok_emb = (const float*)d_in[1];
  const float* pos_emb = (const float*)d_in[2];
  const float* Wq      = (const float*)d_in[3];
  const float* Wk      = (const float*)d_in[4];
  const float* Wv      = (const float*)d_in[5];
  const float* Wo      = (const float*)d_in[6];
  const float* bo      = (const float*)d_in[7];
  const float* ln1g    = (const float*)d_in[8];
  const float* ln1b    = (const float*)d_in[9];
  const float* ln2g    = (const float*)d_in[10];
  const float* ln2b    = (const float*)d_in[11];
  const float* W1      = (const float*)d_in[12];
  const float* b1      = (const float*)d_in[13];
  const float* W2      = (const float*)d_in[14];
  const float* b2      = (const float*)d_in[15];
  const float* Wout    = (const float*)d_in[16];
  const float* bout    = (const float*)d_in[17];
  float* out = (float*)d_out;
  short* wp = (short*)d_ws;  // 104448*2 = 208896 B of workspace

  prep_weights<<<(PREP_TOT + 255) / 256, 256, 0, stream>>>(
      Wq, Wk, Wv, Wo, W1, W2, Wout, wp);

  const int B = in_sizes[0] / T_;  // 16384 sequences, 8 per block (2 per wave)
  bert_mfma<<<B / 8, 256, 0, stream>>>(data, tok_emb, pos_emb, bo, ln1g, ln1b,
                                       ln2g, ln2b, b1, b2, bout, wp, out);
}

// Round 8
// 465.806 us; speedup vs baseline: 1.1943x; 1.0264x over previous
//
#include <hip/hip_runtime.h>

#define T_ 16
#define E_ 64
#define V_ 96
#define L_ 4

typedef unsigned int u32;
typedef unsigned short u16;
typedef __attribute__((ext_vector_type(8))) short bf16x8;
typedef __attribute__((ext_vector_type(4))) float f32x4;

#define MFMA(a, b, c) __builtin_amdgcn_mfma_f32_16x16x32_bf16(a, b, c, 0, 0, 0)
#define SCHED_FENCE() __builtin_amdgcn_sched_barrier(0)

// ws layout (bf16/short elements): B-operand layout [n][k] per matrix
#define OFF_TQ 0
#define OFF_TK 16384
#define OFF_TV 32768
#define OFF_TWO 49152
#define OFF_TW1 65536
#define OFF_TW2 81920
#define OFF_TWOUT 98304
#define PREP_TOT 104448

__device__ __forceinline__ short f2b_rne(float f) {  // fp32 -> bf16 RNE (prep only)
  u32 u = __float_as_uint(f);
  u32 r = (u + 0x7fffu + ((u >> 16) & 1u)) >> 16;
  return (short)r;
}
__device__ __forceinline__ float b2f(short s) {
  return __uint_as_float(((u32)(u16)s) << 16);
}
// round-half-up bf16 pack: low short = bf16(a), high short = bf16(b). 3 VALU.
__device__ __forceinline__ u32 pack2_ru(float a, float b) {
  return __builtin_amdgcn_perm(__float_as_uint(a) + 0x8000u,
                               __float_as_uint(b) + 0x8000u, 0x03020706u);
}
// single-element round-half-up bf16 (same numerics as pack2_ru) for ds_write_b16
__device__ __forceinline__ short b16_ru(float f) {
  return (short)((__float_as_uint(f) + 0x8000u) >> 16);
}

// 16-lane-row reduction via DPP row_ror adds: pure VALU, zero LDS-pipe traffic.
template <int N>
__device__ __forceinline__ float ror_add(float x) {
  int y = __builtin_amdgcn_update_dpp(0, __float_as_int(x), 0x120 + N, 0xF, 0xF,
                                      true);
  return x + __int_as_float(y);
}
__device__ __forceinline__ float sum16(float x) {
  x = ror_add<8>(x);
  x = ror_add<4>(x);
  x = ror_add<2>(x);
  x = ror_add<1>(x);
  return x;
}

__global__ void __launch_bounds__(256) prep_weights(
    const float* __restrict__ Wq, const float* __restrict__ Wk,
    const float* __restrict__ Wv, const float* __restrict__ Wo,
    const float* __restrict__ W1, const float* __restrict__ W2,
    const float* __restrict__ Wout, short* __restrict__ wpo) {
  int id = blockIdx.x * 256 + threadIdx.x;
  if (id >= PREP_TOT) return;
  float v;
  if (id < OFF_TWO) {                       // TQ/TK/TV: n = h*16+kq, k = e
    int which = id >> 14;                   // 0=Q,1=K,2=V
    int r = id & 16383;
    int l = r >> 12, n = (r >> 6) & 63, e = r & 63;
    int h = n >> 4, kq = n & 15;
    const float* W = which == 0 ? Wq : (which == 1 ? Wk : Wv);
    v = W[((l * 4 + h) * 64 + e) * 16 + kq];
  } else if (id < OFF_TWOUT) {              // TWo/TW1/TW2: n = out col, k = e
    int id2 = id - OFF_TWO;
    int which = id2 >> 14;                  // 0=Wo,1=W1,2=W2
    int r = id2 & 16383;
    int l = r >> 12, n = (r >> 6) & 63, e = r & 63;
    const float* W = which == 0 ? Wo : (which == 1 ? W1 : W2);
    v = W[(l * 64 + e) * 64 + n];
  } else {                                  // TWout: n = vocab col, k = e
    int r = id - OFF_TWOUT;
    int n = r >> 6, e = r & 63;
    v = Wout[e * 96 + n];
  }
  wpo[id] = f2b_rne(v);
}

// LayerNorm over 64 cols held as 4 n-regs x 16 lanes (same qq group), rows r.
__device__ __forceinline__ void ln16(float vals[4][4]) {
#pragma unroll
  for (int r = 0; r < 4; ++r) {
    float s = vals[0][r] + vals[1][r] + vals[2][r] + vals[3][r];
    s = sum16(s);
    float mean = s * 0.015625f;
    float vv = 0.f;
#pragma unroll
    for (int n = 0; n < 4; ++n) { float d = vals[n][r] - mean; vv = fmaf(d, d, vv); }
    vv = sum16(vv);
    float rst = rsqrtf(vv * 0.015625f + 1e-5f);
#pragma unroll
    for (int n = 0; n < 4; ++n) vals[n][r] = (vals[n][r] - mean) * rst;
  }
}

// 256 threads = 4 waves; wave w handles TWO sequences (blockIdx.x*8 + w*2 + s).
// Occupancy pinned at 4 waves/SIMD by the unified VGPR+AGPR file (~128/wave).
// Latency hiding = 2 independent per-seq chains interleaved inside EVERY phase.
// SPILL FIX (r8): r4-r7 spilled 440-565 MB scratch although hand-counted peak
// live state is only ~75-90 regs. Cause: the pre-RA scheduler hoists the ~48
// independent 4-reg global weight-fragment loads across phase boundaries
// (~190 regs of hoisted loads) to hide latency, then spills the overflow.
// __builtin_amdgcn_sched_barrier(0) at each phase boundary pins loads into
// their phase; within-phase (2 seq x 4 h) scheduling freedom is untouched.
// No __syncthreads: LDS wave-private, DS pipe in-order per wave. Per seq: 2
// arenas, ping-pong per layer; cols 64..71 zero (A-frag upper-K pad).
__global__ void __launch_bounds__(256, 4) bert_mfma(
    const int* __restrict__ data,
    const float* __restrict__ tok_emb, const float* __restrict__ pos_emb,
    const float* __restrict__ bo, const float* __restrict__ ln1g,
    const float* __restrict__ ln1b, const float* __restrict__ ln2g,
    const float* __restrict__ ln2b, const float* __restrict__ b1,
    const float* __restrict__ b2, const float* __restrict__ bout,
    const short* __restrict__ wp, float* __restrict__ out) {
  __shared__ __align__(16) short R[4][2][2][16][72];  // [wave][seq][arena]

  const int w = threadIdx.x >> 6;
  const int lane = threadIdx.x & 63;
  const int m = lane & 15;   // A-row t / B-row / C-col
  const int qq = lane >> 4;  // k-chunk for frags; C rows qq*4+r
  const int seq0 = blockIdx.x * 8 + w * 2;

  short(*cur[2])[72] = {R[w][0][0], R[w][1][0]};
  short(*oth[2])[72] = {R[w][0][1], R[w][1][1]};

  // zero cols 64..71 of all 4 arenas: A-frag upper-K lanes (qq>=2) read here -> 0
  if (lane < 16) {
#pragma unroll
    for (int s = 0; s < 2; ++s) {
      *(float4*)&R[w][s][0][lane][64] = make_float4(0.f, 0.f, 0.f, 0.f);
      *(float4*)&R[w][s][1][lane][64] = make_float4(0.f, 0.f, 0.f, 0.f);
    }
  }

  // ---- embedding: x = tok_emb[data] + pos_emb -> cur[s] bf16 [t][e] ----
#pragma unroll
  for (int s = 0; s < 2; ++s) {
    const int t = lane >> 2;
    const int c0 = (lane & 3) * 16;
    const int tok = data[(seq0 + s) * T_ + t];
    const float4* tp = (const float4*)(tok_emb + tok * E_ + c0);
    const float4* pp = (const float4*)(pos_emb + t * E_ + c0);
    u32 buf[8];
#pragma unroll
    for (int q = 0; q < 4; ++q) {
      float4 a = tp[q], b = pp[q];
      buf[q * 2 + 0] = pack2_ru(a.x + b.x, a.y + b.y);
      buf[q * 2 + 1] = pack2_ru(a.z + b.z, a.w + b.w);
    }
    ((bf16x8*)&cur[s][t][c0])[0] = ((bf16x8*)buf)[0];
    *(bf16x8*)&cur[s][t][c0 + 8] = ((bf16x8*)(buf + 4))[0];
  }

  // residual stream, C-layout regs: xres[s][n][r] = x_s[qq*4+r][n*16+m]
  float xres[2][4][4];
#pragma unroll
  for (int s = 0; s < 2; ++s)
#pragma unroll
    for (int n = 0; n < 4; ++n)
#pragma unroll
      for (int r = 0; r < 4; ++r) xres[s][n][r] = b2f(cur[s][qq * 4 + r][n * 16 + m]);

  const f32x4 z4 = {0.f, 0.f, 0.f, 0.f};
  const int hselA = (qq < 2) ? 16 : 0;               // head stride for A-frag
  const int aoffA = (qq < 2) ? ((qq & 1) * 8) : 64;  // qq>=2 -> zero cols
  const int boff = (qq & 1) * 8;  // B-frag k>=16 multiplied by A zeros

#pragma unroll 1
  for (int l = 0; l < L_; ++l) {
    const short* TQ = wp + OFF_TQ + l * 4096;
    const short* TK = wp + OFF_TK + l * 4096;
    const short* TV = wp + OFF_TV + l * 4096;
    const short* TWO = wp + OFF_TWO + l * 4096;
    const short* TW1 = wp + OFF_TW1 + l * 4096;
    const short* TW2 = wp + OFF_TW2 + l * 4096;

    // phase 1: x A-frags to regs (x in LDS dead afterwards)
    bf16x8 ax0[2], ax1[2];
#pragma unroll
    for (int s = 0; s < 2; ++s) {
      ax0[s] = *(const bf16x8*)&cur[s][m][qq * 8];
      ax1[s] = *(const bf16x8*)&cur[s][m][32 + qq * 8];
    }
    SCHED_FENCE();

    // phase 2a-Q: q -> cur (over x); separate Q/K passes halve live weight
    // frags at peak, s-interleave preserved.
#pragma unroll
    for (int h = 0; h < 4; ++h) {
      const int bn = (h * 16 + m) * 64 + qq * 8;
      bf16x8 bq0 = *(const bf16x8*)(TQ + bn), bq1 = *(const bf16x8*)(TQ + bn + 32);
#pragma unroll
      for (int s = 0; s < 2; ++s) {
        f32x4 qa = MFMA(ax0[s], bq0, z4); qa = MFMA(ax1[s], bq1, qa);
#pragma unroll
        for (int r = 0; r < 4; ++r) cur[s][qq * 4 + r][h * 16 + m] = b16_ru(qa[r]);
      }
    }
    SCHED_FENCE();

    // phase 2a-K: k -> oth
#pragma unroll
    for (int h = 0; h < 4; ++h) {
      const int bn = (h * 16 + m) * 64 + qq * 8;
      bf16x8 bk0 = *(const bf16x8*)(TK + bn), bk1 = *(const bf16x8*)(TK + bn + 32);
#pragma unroll
      for (int s = 0; s < 2; ++s) {
        f32x4 ka = MFMA(ax0[s], bk0, z4); ka = MFMA(ax1[s], bk1, ka);
#pragma unroll
        for (int r = 0; r < 4; ++r) oth[s][qq * 4 + r][h * 16 + m] = b16_ru(ka[r]);
      }
    }
    SCHED_FENCE();

    // phase 3+4 fused per head: S_h = q k^T, p = exp(S/4) -> cur (over q[h];
    // reads of q[h]/k[h] precede the p[h] write in-order on the DS pipe)
#pragma unroll
    for (int h = 0; h < 4; ++h) {
#pragma unroll
      for (int s = 0; s < 2; ++s) {
        bf16x8 aq = *(const bf16x8*)&cur[s][m][h * hselA + aoffA];
        bf16x8 bk = *(const bf16x8*)&oth[s][m][h * 16 + boff];
        f32x4 sc = MFMA(aq, bk, z4);
#pragma unroll
        for (int r = 0; r < 4; ++r) {
          float e = __expf(sc[r] * 0.25f);
          cur[s][qq * 4 + r][h * 16 + m] = b16_ru(e);
        }
      }
    }
    SCHED_FENCE();

    // phase 2b: V -> vT into oth (over k; all k reads done above)
#pragma unroll
    for (int h = 0; h < 4; ++h) {
      const int bn = (h * 16 + m) * 64 + qq * 8;
      bf16x8 bv0 = *(const bf16x8*)(TV + bn), bv1 = *(const bf16x8*)(TV + bn + 32);
#pragma unroll
      for (int s = 0; s < 2; ++s) {
        f32x4 va = MFMA(ax0[s], bv0, z4); va = MFMA(ax1[s], bv1, va);
        // vT[kd][h*16+t]: 4 consecutive t in-lane -> one b64
        *(uint2*)&oth[s][m][h * 16 + qq * 4] =
            make_uint2(pack2_ru(va[0], va[1]), pack2_ru(va[2], va[3]));
      }
    }
    SCHED_FENCE();

    // phase 5+6 fused per head: O_h = p V (rowsum via ones-B MFMA), normalize,
    // concat -> cur (over p[h]; p[h] reads precede the o[h] write in-order)
    {
      const short s1b = (short)0x3F80;
      const bf16x8 ones8 = {s1b, s1b, s1b, s1b, s1b, s1b, s1b, s1b};
#pragma unroll
      for (int h = 0; h < 4; ++h) {
#pragma unroll
        for (int s = 0; s < 2; ++s) {
          bf16x8 ap = *(const bf16x8*)&cur[s][m][h * hselA + aoffA];
          bf16x8 bv = *(const bf16x8*)&oth[s][m][h * 16 + boff];
          f32x4 ot = MFMA(ap, bv, z4);
          f32x4 rs = MFMA(ap, ones8, z4);
#pragma unroll
          for (int r = 0; r < 4; ++r) {
            float o = ot[r] * __builtin_amdgcn_rcpf(rs[r]);
            cur[s][qq * 4 + r][h * 16 + m] = b16_ru(o);
          }
        }
      }
    }
    SCHED_FENCE();

    // phase 7: x1 = LN1(x + o@Wo + bo) -> oth (over vT), xres in place
    {
      bf16x8 ao0[2], ao1[2];
#pragma unroll
      for (int s = 0; s < 2; ++s) {
        ao0[s] = *(const bf16x8*)&cur[s][m][qq * 8];
        ao1[s] = *(const bf16x8*)&cur[s][m][32 + qq * 8];
      }
#pragma unroll
      for (int n = 0; n < 4; ++n) {
        const int bn = (n * 16 + m) * 64 + qq * 8;
        bf16x8 w0 = *(const bf16x8*)(TWO + bn), w1 = *(const bf16x8*)(TWO + bn + 32);
        float bcol = bo[l * E_ + n * 16 + m];
#pragma unroll
        for (int s = 0; s < 2; ++s) {
          f32x4 d = MFMA(ao0[s], w0, z4); d = MFMA(ao1[s], w1, d);
#pragma unroll
          for (int r = 0; r < 4; ++r) xres[s][n][r] += d[r] + bcol;
        }
      }
#pragma unroll
      for (int s = 0; s < 2; ++s) ln16(xres[s]);
#pragma unroll
      for (int n = 0; n < 4; ++n) {
        float g = ln1g[l * E_ + n * 16 + m];
        float bb = ln1b[l * E_ + n * 16 + m];
#pragma unroll
        for (int s = 0; s < 2; ++s)
#pragma unroll
          for (int r = 0; r < 4; ++r) {
            float xv = fmaf(xres[s][n][r], g, bb);
            xres[s][n][r] = xv;
            oth[s][qq * 4 + r][n * 16 + m] = b16_ru(xv);
          }
      }
    }
    SCHED_FENCE();

    // phase 8: h1 = relu(x1@W1 + b1) -> cur (over ob)
    {
      bf16x8 a10[2], a11[2];
#pragma unroll
      for (int s = 0; s < 2; ++s) {
        a10[s] = *(const bf16x8*)&oth[s][m][qq * 8];
        a11[s] = *(const bf16x8*)&oth[s][m][32 + qq * 8];
      }
#pragma unroll
      for (int n = 0; n < 4; ++n) {
        const int bn = (n * 16 + m) * 64 + qq * 8;
        bf16x8 w0 = *(const bf16x8*)(TW1 + bn), w1 = *(const bf16x8*)(TW1 + bn + 32);
        float bcol = b1[l * E_ + n * 16 + m];
#pragma unroll
        for (int s = 0; s < 2; ++s) {
          f32x4 acc = MFMA(a10[s], w0, z4); acc = MFMA(a11[s], w1, acc);
#pragma unroll
          for (int r = 0; r < 4; ++r) {
            float hv = fmaxf(acc[r] + bcol, 0.f);
            cur[s][qq * 4 + r][n * 16 + m] = b16_ru(hv);
          }
        }
      }
    }
    SCHED_FENCE();

    // phase 9: x = LN2(x1 + h1@W2 + b2) -> oth (over x1), xres in place
    {
      bf16x8 a20[2], a21[2];
#pragma unroll
      for (int s = 0; s < 2; ++s) {
        a20[s] = *(const bf16x8*)&cur[s][m][qq * 8];
        a21[s] = *(const bf16x8*)&cur[s][m][32 + qq * 8];
      }
#pragma unroll
      for (int n = 0; n < 4; ++n) {
        const int bn = (n * 16 + m) * 64 + qq * 8;
        bf16x8 w0 = *(const bf16x8*)(TW2 + bn), w1 = *(const bf16x8*)(TW2 + bn + 32);
        float bcol = b2[l * E_ + n * 16 + m];
#pragma unroll
        for (int s = 0; s < 2; ++s) {
          f32x4 d = MFMA(a20[s], w0, z4); d = MFMA(a21[s], w1, d);
#pragma unroll
          for (int r = 0; r < 4; ++r) xres[s][n][r] += d[r] + bcol;
        }
      }
#pragma unroll
      for (int s = 0; s < 2; ++s) ln16(xres[s]);
#pragma unroll
      for (int n = 0; n < 4; ++n) {
        float g = ln2g[l * E_ + n * 16 + m];
        float bb = ln2b[l * E_ + n * 16 + m];
#pragma unroll
        for (int s = 0; s < 2; ++s)
#pragma unroll
          for (int r = 0; r < 4; ++r) {
            float xv = fmaf(xres[s][n][r], g, bb);
            xres[s][n][r] = xv;
            oth[s][qq * 4 + r][n * 16 + m] = b16_ru(xv);
          }
      }
    }
    SCHED_FENCE();

    // ping-pong arenas: next layer's x is in oth
#pragma unroll
    for (int s = 0; s < 2; ++s) {
      short(*tmp)[72] = cur[s]; cur[s] = oth[s]; oth[s] = tmp;
    }
  }

  // epilogue: logits = x @ Wout + bout (6 n-tiles), fp32 coalesced stores
  {
    bf16x8 af0[2], af1[2];
#pragma unroll
    for (int s = 0; s < 2; ++s) {
      af0[s] = *(const bf16x8*)&cur[s][m][qq * 8];
      af1[s] = *(const bf16x8*)&cur[s][m][32 + qq * 8];
    }
    const short* TWOUT = wp + OFF_TWOUT;
#pragma unroll
    for (int n = 0; n < 6; ++n) {
      const int bn = (n * 16 + m) * 64 + qq * 8;
      bf16x8 w0 = *(const bf16x8*)(TWOUT + bn), w1 = *(const bf16x8*)(TWOUT + bn + 32);
      float bcol = bout[n * 16 + m];
#pragma unroll
      for (int s = 0; s < 2; ++s) {
        f32x4 acc = MFMA(af0[s], w0, z4); acc = MFMA(af1[s], w1, acc);
#pragma unroll
        for (int r = 0; r < 4; ++r)
          out[((seq0 + s) * T_ + qq * 4 + r) * V_ + n * 16 + m] = acc[r] + bcol;
      }
    }
  }
}

extern "C" void kernel_launch(void* const* d_in, const int* in_sizes, int n_in,
                              void* d_out, int out_size, void* d_ws, size_t ws_size,
                              hipStream_t stream) {
  const int*   data    = (const int*)d_in[0];
  const float* tok_emb = (const float*)d_in[1];
  const float* pos_emb = (const float*)d_in[2];
  const float* Wq      = (const float*)d_in[3];
  const float* Wk      = (const float*)d_in[4];
  const float* Wv      = (const float*)d_in[5];
  const float* Wo      = (const float*)d_in[6];
  const float* bo      = (const float*)d_in[7];
  const float* ln1g    = (const float*)d_in[8];
  const float* ln1b    = (const float*)d_in[9];
  const float* ln2g    = (const float*)d_in[10];
  const float* ln2b    = (const float*)d_in[11];
  const float* W1      = (const float*)d_in[12];
  const float* b1      = (const float*)d_in[13];
  const float* W2      = (const float*)d_in[14];
  const float* b2      = (const float*)d_in[15];
  const float* Wout    = (const float*)d_in[16];
  const float* bout    = (const float*)d_in[17];
  float* out = (float*)d_out;
  short* wp = (short*)d_ws;  // 104448*2 = 208896 B of workspace

  prep_weights<<<(PREP_TOT + 255) / 256, 256, 0, stream>>>(
      Wq, Wk, Wv, Wo, W1, W2, Wout, wp);

  const int B = in_sizes[0] / T_;  // 16384 sequences, 8 per block (2 per wave)
  bert_mfma<<<B / 8, 256, 0, stream>>>(data, tok_emb, pos_emb, bo, ln1g, ln1b,
                                       ln2g, ln2b, b1, b2, bout, wp, out);
}

// Round 9
// 438.137 us; speedup vs baseline: 1.2698x; 1.0632x over previous
//
#include <hip/hip_runtime.h>

#define T_ 16
#define E_ 64
#define V_ 96
#define L_ 4

typedef unsigned int u32;
typedef unsigned short u16;
typedef __attribute__((ext_vector_type(8))) short bf16x8;
typedef __attribute__((ext_vector_type(4))) float f32x4;

#define MFMA(a, b, c) __builtin_amdgcn_mfma_f32_16x16x32_bf16(a, b, c, 0, 0, 0)
#define SCHED_FENCE() __builtin_amdgcn_sched_barrier(0)

// ws layout (bf16/short elements): B-operand layout [n][k] per matrix
#define OFF_TQ 0
#define OFF_TK 16384
#define OFF_TV 32768
#define OFF_TWO 49152
#define OFF_TW1 65536
#define OFF_TW2 81920
#define OFF_TWOUT 98304
#define PREP_TOT 104448

__device__ __forceinline__ short f2b_rne(float f) {  // fp32 -> bf16 RNE (prep only)
  u32 u = __float_as_uint(f);
  u32 r = (u + 0x7fffu + ((u >> 16) & 1u)) >> 16;
  return (short)r;
}
__device__ __forceinline__ float b2f(short s) {
  return __uint_as_float(((u32)(u16)s) << 16);
}
// round-half-up bf16 pack: low short = bf16(a), high short = bf16(b). 3 VALU.
__device__ __forceinline__ u32 pack2_ru(float a, float b) {
  return __builtin_amdgcn_perm(__float_as_uint(a) + 0x8000u,
                               __float_as_uint(b) + 0x8000u, 0x03020706u);
}
// single-element round-half-up bf16 (same numerics as pack2_ru) for ds_write_b16
__device__ __forceinline__ short b16_ru(float f) {
  return (short)((__float_as_uint(f) + 0x8000u) >> 16);
}

// 16-lane-row reduction via DPP row_ror adds: pure VALU, zero LDS-pipe traffic.
template <int N>
__device__ __forceinline__ float ror_add(float x) {
  int y = __builtin_amdgcn_update_dpp(0, __float_as_int(x), 0x120 + N, 0xF, 0xF,
                                      true);
  return x + __int_as_float(y);
}
__device__ __forceinline__ float sum16(float x) {
  x = ror_add<8>(x);
  x = ror_add<4>(x);
  x = ror_add<2>(x);
  x = ror_add<1>(x);
  return x;
}

__global__ void __launch_bounds__(256) prep_weights(
    const float* __restrict__ Wq, const float* __restrict__ Wk,
    const float* __restrict__ Wv, const float* __restrict__ Wo,
    const float* __restrict__ W1, const float* __restrict__ W2,
    const float* __restrict__ Wout, short* __restrict__ wpo) {
  int id = blockIdx.x * 256 + threadIdx.x;
  if (id >= PREP_TOT) return;
  float v;
  if (id < OFF_TWO) {                       // TQ/TK/TV: n = h*16+kq, k = e
    int which = id >> 14;                   // 0=Q,1=K,2=V
    int r = id & 16383;
    int l = r >> 12, n = (r >> 6) & 63, e = r & 63;
    int h = n >> 4, kq = n & 15;
    const float* W = which == 0 ? Wq : (which == 1 ? Wk : Wv);
    v = W[((l * 4 + h) * 64 + e) * 16 + kq];
  } else if (id < OFF_TWOUT) {              // TWo/TW1/TW2: n = out col, k = e
    int id2 = id - OFF_TWO;
    int which = id2 >> 14;                  // 0=Wo,1=W1,2=W2
    int r = id2 & 16383;
    int l = r >> 12, n = (r >> 6) & 63, e = r & 63;
    const float* W = which == 0 ? Wo : (which == 1 ? W1 : W2);
    v = W[(l * 64 + e) * 64 + n];
  } else {                                  // TWout: n = vocab col, k = e
    int r = id - OFF_TWOUT;
    int n = r >> 6, e = r & 63;
    v = Wout[e * 96 + n];
  }
  wpo[id] = f2b_rne(v);
}

// LayerNorm over 64 cols held as 4 n-regs x 16 lanes (same qq group), rows r.
__device__ __forceinline__ void ln16(float vals[4][4]) {
#pragma unroll
  for (int r = 0; r < 4; ++r) {
    float s = vals[0][r] + vals[1][r] + vals[2][r] + vals[3][r];
    s = sum16(s);
    float mean = s * 0.015625f;
    float vv = 0.f;
#pragma unroll
    for (int n = 0; n < 4; ++n) { float d = vals[n][r] - mean; vv = fmaf(d, d, vv); }
    vv = sum16(vv);
    float rst = rsqrtf(vv * 0.015625f + 1e-5f);
#pragma unroll
    for (int n = 0; n < 4; ++n) vals[n][r] = (vals[n][r] - mean) * rst;
  }
}

// 256 threads = 4 waves; wave w handles TWO sequences (blockIdx.x*8 + w*2 + s).
// REGISTER-BUDGET FIX (r9): on gfx950's unified RF the (256,4) bound gives a
// 128-reg total budget which the compiler splits 64 arch-VGPR + 64 AGPR
// (accum_offset); the 2-chain scalar state needs ~100 arch regs, so every
// (256,4) build spilled 450+ MB scratch with VGPR_Count pinned at exactly 64
// (r4-r8; source-level trims never got under it). launch_bounds(256,3) raises
// the budget to ~170 total (~106 arch): zero spill at the cost of runtime
// occupancy 16 -> 12 waves/CU. 12 waves x 2 chains = 24 independent chains/CU
// beats 16 spill-throttled waves (r4: 367 us) and 16 clean 1-chain waves
// (r3: 419 us). Phase-boundary sched_barrier(0) retained from r8 (limits
// cross-phase load hoisting; keeps live ranges phase-local).
// No __syncthreads: LDS wave-private, DS pipe in-order per wave. Per seq: 2
// arenas, ping-pong per layer; cols 64..71 zero (A-frag upper-K pad).
__global__ void __launch_bounds__(256, 3) bert_mfma(
    const int* __restrict__ data,
    const float* __restrict__ tok_emb, const float* __restrict__ pos_emb,
    const float* __restrict__ bo, const float* __restrict__ ln1g,
    const float* __restrict__ ln1b, const float* __restrict__ ln2g,
    const float* __restrict__ ln2b, const float* __restrict__ b1,
    const float* __restrict__ b2, const float* __restrict__ bout,
    const short* __restrict__ wp, float* __restrict__ out) {
  __shared__ __align__(16) short R[4][2][2][16][72];  // [wave][seq][arena]

  const int w = threadIdx.x >> 6;
  const int lane = threadIdx.x & 63;
  const int m = lane & 15;   // A-row t / B-row / C-col
  const int qq = lane >> 4;  // k-chunk for frags; C rows qq*4+r
  const int seq0 = blockIdx.x * 8 + w * 2;

  short(*cur[2])[72] = {R[w][0][0], R[w][1][0]};
  short(*oth[2])[72] = {R[w][0][1], R[w][1][1]};

  // zero cols 64..71 of all 4 arenas: A-frag upper-K lanes (qq>=2) read here -> 0
  if (lane < 16) {
#pragma unroll
    for (int s = 0; s < 2; ++s) {
      *(float4*)&R[w][s][0][lane][64] = make_float4(0.f, 0.f, 0.f, 0.f);
      *(float4*)&R[w][s][1][lane][64] = make_float4(0.f, 0.f, 0.f, 0.f);
    }
  }

  // ---- embedding: x = tok_emb[data] + pos_emb -> cur[s] bf16 [t][e] ----
#pragma unroll
  for (int s = 0; s < 2; ++s) {
    const int t = lane >> 2;
    const int c0 = (lane & 3) * 16;
    const int tok = data[(seq0 + s) * T_ + t];
    const float4* tp = (const float4*)(tok_emb + tok * E_ + c0);
    const float4* pp = (const float4*)(pos_emb + t * E_ + c0);
    u32 buf[8];
#pragma unroll
    for (int q = 0; q < 4; ++q) {
      float4 a = tp[q], b = pp[q];
      buf[q * 2 + 0] = pack2_ru(a.x + b.x, a.y + b.y);
      buf[q * 2 + 1] = pack2_ru(a.z + b.z, a.w + b.w);
    }
    ((bf16x8*)&cur[s][t][c0])[0] = ((bf16x8*)buf)[0];
    *(bf16x8*)&cur[s][t][c0 + 8] = ((bf16x8*)(buf + 4))[0];
  }

  // residual stream, C-layout regs: xres[s][n][r] = x_s[qq*4+r][n*16+m]
  float xres[2][4][4];
#pragma unroll
  for (int s = 0; s < 2; ++s)
#pragma unroll
    for (int n = 0; n < 4; ++n)
#pragma unroll
      for (int r = 0; r < 4; ++r) xres[s][n][r] = b2f(cur[s][qq * 4 + r][n * 16 + m]);

  const f32x4 z4 = {0.f, 0.f, 0.f, 0.f};
  const int hselA = (qq < 2) ? 16 : 0;               // head stride for A-frag
  const int aoffA = (qq < 2) ? ((qq & 1) * 8) : 64;  // qq>=2 -> zero cols
  const int boff = (qq & 1) * 8;  // B-frag k>=16 multiplied by A zeros

#pragma unroll 1
  for (int l = 0; l < L_; ++l) {
    const short* TQ = wp + OFF_TQ + l * 4096;
    const short* TK = wp + OFF_TK + l * 4096;
    const short* TV = wp + OFF_TV + l * 4096;
    const short* TWO = wp + OFF_TWO + l * 4096;
    const short* TW1 = wp + OFF_TW1 + l * 4096;
    const short* TW2 = wp + OFF_TW2 + l * 4096;

    // phase 1: x A-frags to regs (x in LDS dead afterwards)
    bf16x8 ax0[2], ax1[2];
#pragma unroll
    for (int s = 0; s < 2; ++s) {
      ax0[s] = *(const bf16x8*)&cur[s][m][qq * 8];
      ax1[s] = *(const bf16x8*)&cur[s][m][32 + qq * 8];
    }
    SCHED_FENCE();

    // phase 2a-Q: q -> cur (over x); separate Q/K passes halve live weight
    // frags at peak, s-interleave preserved.
#pragma unroll
    for (int h = 0; h < 4; ++h) {
      const int bn = (h * 16 + m) * 64 + qq * 8;
      bf16x8 bq0 = *(const bf16x8*)(TQ + bn), bq1 = *(const bf16x8*)(TQ + bn + 32);
#pragma unroll
      for (int s = 0; s < 2; ++s) {
        f32x4 qa = MFMA(ax0[s], bq0, z4); qa = MFMA(ax1[s], bq1, qa);
#pragma unroll
        for (int r = 0; r < 4; ++r) cur[s][qq * 4 + r][h * 16 + m] = b16_ru(qa[r]);
      }
    }
    SCHED_FENCE();

    // phase 2a-K: k -> oth
#pragma unroll
    for (int h = 0; h < 4; ++h) {
      const int bn = (h * 16 + m) * 64 + qq * 8;
      bf16x8 bk0 = *(const bf16x8*)(TK + bn), bk1 = *(const bf16x8*)(TK + bn + 32);
#pragma unroll
      for (int s = 0; s < 2; ++s) {
        f32x4 ka = MFMA(ax0[s], bk0, z4); ka = MFMA(ax1[s], bk1, ka);
#pragma unroll
        for (int r = 0; r < 4; ++r) oth[s][qq * 4 + r][h * 16 + m] = b16_ru(ka[r]);
      }
    }
    SCHED_FENCE();

    // phase 3+4 fused per head: S_h = q k^T, p = exp(S/4) -> cur (over q[h];
    // reads of q[h]/k[h] precede the p[h] write in-order on the DS pipe)
#pragma unroll
    for (int h = 0; h < 4; ++h) {
#pragma unroll
      for (int s = 0; s < 2; ++s) {
        bf16x8 aq = *(const bf16x8*)&cur[s][m][h * hselA + aoffA];
        bf16x8 bk = *(const bf16x8*)&oth[s][m][h * 16 + boff];
        f32x4 sc = MFMA(aq, bk, z4);
#pragma unroll
        for (int r = 0; r < 4; ++r) {
          float e = __expf(sc[r] * 0.25f);
          cur[s][qq * 4 + r][h * 16 + m] = b16_ru(e);
        }
      }
    }
    SCHED_FENCE();

    // phase 2b: V -> vT into oth (over k; all k reads done above)
#pragma unroll
    for (int h = 0; h < 4; ++h) {
      const int bn = (h * 16 + m) * 64 + qq * 8;
      bf16x8 bv0 = *(const bf16x8*)(TV + bn), bv1 = *(const bf16x8*)(TV + bn + 32);
#pragma unroll
      for (int s = 0; s < 2; ++s) {
        f32x4 va = MFMA(ax0[s], bv0, z4); va = MFMA(ax1[s], bv1, va);
        // vT[kd][h*16+t]: 4 consecutive t in-lane -> one b64
        *(uint2*)&oth[s][m][h * 16 + qq * 4] =
            make_uint2(pack2_ru(va[0], va[1]), pack2_ru(va[2], va[3]));
      }
    }
    SCHED_FENCE();

    // phase 5+6 fused per head: O_h = p V (rowsum via ones-B MFMA), normalize,
    // concat -> cur (over p[h]; p[h] reads precede the o[h] write in-order)
    {
      const short s1b = (short)0x3F80;
      const bf16x8 ones8 = {s1b, s1b, s1b, s1b, s1b, s1b, s1b, s1b};
#pragma unroll
      for (int h = 0; h < 4; ++h) {
#pragma unroll
        for (int s = 0; s < 2; ++s) {
          bf16x8 ap = *(const bf16x8*)&cur[s][m][h * hselA + aoffA];
          bf16x8 bv = *(const bf16x8*)&oth[s][m][h * 16 + boff];
          f32x4 ot = MFMA(ap, bv, z4);
          f32x4 rs = MFMA(ap, ones8, z4);
#pragma unroll
          for (int r = 0; r < 4; ++r) {
            float o = ot[r] * __builtin_amdgcn_rcpf(rs[r]);
            cur[s][qq * 4 + r][h * 16 + m] = b16_ru(o);
          }
        }
      }
    }
    SCHED_FENCE();

    // phase 7: x1 = LN1(x + o@Wo + bo) -> oth (over vT), xres in place
    {
      bf16x8 ao0[2], ao1[2];
#pragma unroll
      for (int s = 0; s < 2; ++s) {
        ao0[s] = *(const bf16x8*)&cur[s][m][qq * 8];
        ao1[s] = *(const bf16x8*)&cur[s][m][32 + qq * 8];
      }
#pragma unroll
      for (int n = 0; n < 4; ++n) {
        const int bn = (n * 16 + m) * 64 + qq * 8;
        bf16x8 w0 = *(const bf16x8*)(TWO + bn), w1 = *(const bf16x8*)(TWO + bn + 32);
        float bcol = bo[l * E_ + n * 16 + m];
#pragma unroll
        for (int s = 0; s < 2; ++s) {
          f32x4 d = MFMA(ao0[s], w0, z4); d = MFMA(ao1[s], w1, d);
#pragma unroll
          for (int r = 0; r < 4; ++r) xres[s][n][r] += d[r] + bcol;
        }
      }
#pragma unroll
      for (int s = 0; s < 2; ++s) ln16(xres[s]);
#pragma unroll
      for (int n = 0; n < 4; ++n) {
        float g = ln1g[l * E_ + n * 16 + m];
        float bb = ln1b[l * E_ + n * 16 + m];
#pragma unroll
        for (int s = 0; s < 2; ++s)
#pragma unroll
          for (int r = 0; r < 4; ++r) {
            float xv = fmaf(xres[s][n][r], g, bb);
            xres[s][n][r] = xv;
            oth[s][qq * 4 + r][n * 16 + m] = b16_ru(xv);
          }
      }
    }
    SCHED_FENCE();

    // phase 8: h1 = relu(x1@W1 + b1) -> cur (over ob)
    {
      bf16x8 a10[2], a11[2];
#pragma unroll
      for (int s = 0; s < 2; ++s) {
        a10[s] = *(const bf16x8*)&oth[s][m][qq * 8];
        a11[s] = *(const bf16x8*)&oth[s][m][32 + qq * 8];
      }
#pragma unroll
      for (int n = 0; n < 4; ++n) {
        const int bn = (n * 16 + m) * 64 + qq * 8;
        bf16x8 w0 = *(const bf16x8*)(TW1 + bn), w1 = *(const bf16x8*)(TW1 + bn + 32);
        float bcol = b1[l * E_ + n * 16 + m];
#pragma unroll
        for (int s = 0; s < 2; ++s) {
          f32x4 acc = MFMA(a10[s], w0, z4); acc = MFMA(a11[s], w1, acc);
#pragma unroll
          for (int r = 0; r < 4; ++r) {
            float hv = fmaxf(acc[r] + bcol, 0.f);
            cur[s][qq * 4 + r][n * 16 + m] = b16_ru(hv);
          }
        }
      }
    }
    SCHED_FENCE();

    // phase 9: x = LN2(x1 + h1@W2 + b2) -> oth (over x1), xres in place
    {
      bf16x8 a20[2], a21[2];
#pragma unroll
      for (int s = 0; s < 2; ++s) {
        a20[s] = *(const bf16x8*)&cur[s][m][qq * 8];
        a21[s] = *(const bf16x8*)&cur[s][m][32 + qq * 8];
      }
#pragma unroll
      for (int n = 0; n < 4; ++n) {
        const int bn = (n * 16 + m) * 64 + qq * 8;
        bf16x8 w0 = *(const bf16x8*)(TW2 + bn), w1 = *(const bf16x8*)(TW2 + bn + 32);
        float bcol = b2[l * E_ + n * 16 + m];
#pragma unroll
        for (int s = 0; s < 2; ++s) {
          f32x4 d = MFMA(a20[s], w0, z4); d = MFMA(a21[s], w1, d);
#pragma unroll
          for (int r = 0; r < 4; ++r) xres[s][n][r] += d[r] + bcol;
        }
      }
#pragma unroll
      for (int s = 0; s < 2; ++s) ln16(xres[s]);
#pragma unroll
      for (int n = 0; n < 4; ++n) {
        float g = ln2g[l * E_ + n * 16 + m];
        float bb = ln2b[l * E_ + n * 16 + m];
#pragma unroll
        for (int s = 0; s < 2; ++s)
#pragma unroll
          for (int r = 0; r < 4; ++r) {
            float xv = fmaf(xres[s][n][r], g, bb);
            xres[s][n][r] = xv;
            oth[s][qq * 4 + r][n * 16 + m] = b16_ru(xv);
          }
      }
    }
    SCHED_FENCE();

    // ping-pong arenas: next layer's x is in oth
#pragma unroll
    for (int s = 0; s < 2; ++s) {
      short(*tmp)[72] = cur[s]; cur[s] = oth[s]; oth[s] = tmp;
    }
  }

  // epilogue: logits = x @ Wout + bout (6 n-tiles), fp32 coalesced stores
  {
    bf16x8 af0[2], af1[2];
#pragma unroll
    for (int s = 0; s < 2; ++s) {
      af0[s] = *(const bf16x8*)&cur[s][m][qq * 8];
      af1[s] = *(const bf16x8*)&cur[s][m][32 + qq * 8];
    }
    const short* TWOUT = wp + OFF_TWOUT;
#pragma unroll
    for (int n = 0; n < 6; ++n) {
      const int bn = (n * 16 + m) * 64 + qq * 8;
      bf16x8 w0 = *(const bf16x8*)(TWOUT + bn), w1 = *(const bf16x8*)(TWOUT + bn + 32);
      float bcol = bout[n * 16 + m];
#pragma unroll
      for (int s = 0; s < 2; ++s) {
        f32x4 acc = MFMA(af0[s], w0, z4); acc = MFMA(af1[s], w1, acc);
#pragma unroll
        for (int r = 0; r < 4; ++r)
          out[((seq0 + s) * T_ + qq * 4 + r) * V_ + n * 16 + m] = acc[r] + bcol;
      }
    }
  }
}

extern "C" void kernel_launch(void* const* d_in, const int* in_sizes, int n_in,
                              void* d_out, int out_size, void* d_ws, size_t ws_size,
                              hipStream_t stream) {
  const int*   data    = (const int*)d_in[0];
  const float* tok_emb = (const float*)d_in[1];
  const float* pos_emb = (const float*)d_in[2];
  const float* Wq      = (const float*)d_in[3];
  const float* Wk      = (const float*)d_in[4];
  const float* Wv      = (const float*)d_in[5];
  const float* Wo      = (const float*)d_in[6];
  const float* bo      = (const float*)d_in[7];
  const float* ln1g    = (const float*)d_in[8];
  const float* ln1b    = (const float*)d_in[9];
  const float* ln2g    = (const float*)d_in[10];
  const float* ln2b    = (const float*)d_in[11];
  const float* W1      = (const float*)d_in[12];
  const float* b1      = (const float*)d_in[13];
  const float* W2      = (const float*)d_in[14];
  const float* b2      = (const float*)d_in[15];
  const float* Wout    = (const float*)d_in[16];
  const float* bout    = (const float*)d_in[17];
  float* out = (float*)d_out;
  short* wp = (short*)d_ws;  // 104448*2 = 208896 B of workspace

  prep_weights<<<(PREP_TOT + 255) / 256, 256, 0, stream>>>(
      Wq, Wk, Wv, Wo, W1, W2, Wout, wp);

  const int B = in_sizes[0] / T_;  // 16384 sequences, 8 per block (2 per wave)
  bert_mfma<<<B / 8, 256, 0, stream>>>(data, tok_emb, pos_emb, bo, ln1g, ln1b,
                                       ln2g, ln2b, b1, b2, bout, wp, out);
}

// Round 10
// 407.468 us; speedup vs baseline: 1.3653x; 1.0753x over previous
//
#include <hip/hip_runtime.h>

#define T_ 16
#define E_ 64
#define V_ 96
#define L_ 4

typedef unsigned int u32;
typedef unsigned short u16;
typedef __attribute__((ext_vector_type(8))) short bf16x8;
typedef __attribute__((ext_vector_type(4))) float f32x4;

#define MFMA(a, b, c) __builtin_amdgcn_mfma_f32_16x16x32_bf16(a, b, c, 0, 0, 0)
#define SCHED_FENCE() __builtin_amdgcn_sched_barrier(0)

// ws layout (bf16/short elements): B-operand layout [n][k] per matrix
#define OFF_TQ 0
#define OFF_TK 16384
#define OFF_TV 32768
#define OFF_TWO 49152
#define OFF_TW1 65536
#define OFF_TW2 81920
#define OFF_TWOUT 98304
#define PREP_TOT 104448

__device__ __forceinline__ short f2b_rne(float f) {  // fp32 -> bf16 RNE (prep only)
  u32 u = __float_as_uint(f);
  u32 r = (u + 0x7fffu + ((u >> 16) & 1u)) >> 16;
  return (short)r;
}
__device__ __forceinline__ float b2f(short s) {
  return __uint_as_float(((u32)(u16)s) << 16);
}
// round-half-up bf16 pack: low short = bf16(a), high short = bf16(b). 3 VALU.
__device__ __forceinline__ u32 pack2_ru(float a, float b) {
  return __builtin_amdgcn_perm(__float_as_uint(a) + 0x8000u,
                               __float_as_uint(b) + 0x8000u, 0x03020706u);
}
// single-element round-half-up bf16 (same numerics as pack2_ru) for ds_write_b16
__device__ __forceinline__ short b16_ru(float f) {
  return (short)((__float_as_uint(f) + 0x8000u) >> 16);
}

// 16-lane-row reduction via DPP row_ror adds: pure VALU, zero LDS-pipe traffic.
template <int N>
__device__ __forceinline__ float ror_add(float x) {
  int y = __builtin_amdgcn_update_dpp(0, __float_as_int(x), 0x120 + N, 0xF, 0xF,
                                      true);
  return x + __int_as_float(y);
}
__device__ __forceinline__ float sum16(float x) {
  x = ror_add<8>(x);
  x = ror_add<4>(x);
  x = ror_add<2>(x);
  x = ror_add<1>(x);
  return x;
}

__global__ void __launch_bounds__(256) prep_weights(
    const float* __restrict__ Wq, const float* __restrict__ Wk,
    const float* __restrict__ Wv, const float* __restrict__ Wo,
    const float* __restrict__ W1, const float* __restrict__ W2,
    const float* __restrict__ Wout, short* __restrict__ wpo) {
  int id = blockIdx.x * 256 + threadIdx.x;
  if (id >= PREP_TOT) return;
  float v;
  if (id < OFF_TWO) {                       // TQ/TK/TV: n = h*16+kq, k = e
    int which = id >> 14;                   // 0=Q,1=K,2=V
    int r = id & 16383;
    int l = r >> 12, n = (r >> 6) & 63, e = r & 63;
    int h = n >> 4, kq = n & 15;
    const float* W = which == 0 ? Wq : (which == 1 ? Wk : Wv);
    v = W[((l * 4 + h) * 64 + e) * 16 + kq];
  } else if (id < OFF_TWOUT) {              // TWo/TW1/TW2: n = out col, k = e
    int id2 = id - OFF_TWO;
    int which = id2 >> 14;                  // 0=Wo,1=W1,2=W2
    int r = id2 & 16383;
    int l = r >> 12, n = (r >> 6) & 63, e = r & 63;
    const float* W = which == 0 ? Wo : (which == 1 ? W1 : W2);
    v = W[(l * 64 + e) * 64 + n];
  } else {                                  // TWout: n = vocab col, k = e
    int r = id - OFF_TWOUT;
    int n = r >> 6, e = r & 63;
    v = Wout[e * 96 + n];
  }
  wpo[id] = f2b_rne(v);
}

// LayerNorm over 64 cols held as 4 n-regs x 16 lanes (same qq group), rows r.
__device__ __forceinline__ void ln16(float vals[4][4]) {
#pragma unroll
  for (int r = 0; r < 4; ++r) {
    float s = vals[0][r] + vals[1][r] + vals[2][r] + vals[3][r];
    s = sum16(s);
    float mean = s * 0.015625f;
    float vv = 0.f;
#pragma unroll
    for (int n = 0; n < 4; ++n) { float d = vals[n][r] - mean; vv = fmaf(d, d, vv); }
    vv = sum16(vv);
    float rst = rsqrtf(vv * 0.015625f + 1e-5f);
#pragma unroll
    for (int n = 0; n < 4; ++n) vals[n][r] = (vals[n][r] - mean) * rst;
  }
}

// 256 threads = 4 waves; wave w handles TWO sequences (blockIdx.x*8 + w*2 + s).
// I-FETCH FIX (r10): per-wave latency is ~100 us in EVERY round (r1/r3/r4/r9:
// dur x resident-waves / wave-jobs) with all exec pipes <25% busy — and the
// only lever that ever cut per-seq latency was ILP=2 (one fetch stream, two
// seqs). Diagnosis: the fully-unrolled layer body (~3000+ instr, 20+ KB)
// thrashes the per-CU I-cache with 12 unsynchronized waves; every line is an
// L2 fetch. Fix: head-loops (2a-Q/2a-K/3+4/2b/5+6), phase-8 n-loop, and the
// epilogue n-loop become runtime loops (#pragma unroll 1) — ~1200 instr body
// fits I-cache. Phases 7/9 keep n unrolled (they index xres; rule #20).
// Register model (r9-confirmed): unified RF, budget split arch/AGPR halves;
// (256,3) => ~170 total budget, no forced spill. Phase-boundary
// sched_barrier(0) retained. No __syncthreads: LDS wave-private, DS pipe
// in-order per wave. Per seq: 2 arenas ping-pong; cols 64..71 zero (A pad).
__global__ void __launch_bounds__(256, 3) bert_mfma(
    const int* __restrict__ data,
    const float* __restrict__ tok_emb, const float* __restrict__ pos_emb,
    const float* __restrict__ bo, const float* __restrict__ ln1g,
    const float* __restrict__ ln1b, const float* __restrict__ ln2g,
    const float* __restrict__ ln2b, const float* __restrict__ b1,
    const float* __restrict__ b2, const float* __restrict__ bout,
    const short* __restrict__ wp, float* __restrict__ out) {
  __shared__ __align__(16) short R[4][2][2][16][72];  // [wave][seq][arena]

  const int w = threadIdx.x >> 6;
  const int lane = threadIdx.x & 63;
  const int m = lane & 15;   // A-row t / B-row / C-col
  const int qq = lane >> 4;  // k-chunk for frags; C rows qq*4+r
  const int seq0 = blockIdx.x * 8 + w * 2;

  short(*cur[2])[72] = {R[w][0][0], R[w][1][0]};
  short(*oth[2])[72] = {R[w][0][1], R[w][1][1]};

  // zero cols 64..71 of all 4 arenas: A-frag upper-K lanes (qq>=2) read here -> 0
  if (lane < 16) {
#pragma unroll
    for (int s = 0; s < 2; ++s) {
      *(float4*)&R[w][s][0][lane][64] = make_float4(0.f, 0.f, 0.f, 0.f);
      *(float4*)&R[w][s][1][lane][64] = make_float4(0.f, 0.f, 0.f, 0.f);
    }
  }

  // ---- embedding: x = tok_emb[data] + pos_emb -> cur[s] bf16 [t][e] ----
#pragma unroll
  for (int s = 0; s < 2; ++s) {
    const int t = lane >> 2;
    const int c0 = (lane & 3) * 16;
    const int tok = data[(seq0 + s) * T_ + t];
    const float4* tp = (const float4*)(tok_emb + tok * E_ + c0);
    const float4* pp = (const float4*)(pos_emb + t * E_ + c0);
    u32 buf[8];
#pragma unroll
    for (int q = 0; q < 4; ++q) {
      float4 a = tp[q], b = pp[q];
      buf[q * 2 + 0] = pack2_ru(a.x + b.x, a.y + b.y);
      buf[q * 2 + 1] = pack2_ru(a.z + b.z, a.w + b.w);
    }
    ((bf16x8*)&cur[s][t][c0])[0] = ((bf16x8*)buf)[0];
    *(bf16x8*)&cur[s][t][c0 + 8] = ((bf16x8*)(buf + 4))[0];
  }

  // residual stream, C-layout regs: xres[s][n][r] = x_s[qq*4+r][n*16+m]
  float xres[2][4][4];
#pragma unroll
  for (int s = 0; s < 2; ++s)
#pragma unroll
    for (int n = 0; n < 4; ++n)
#pragma unroll
      for (int r = 0; r < 4; ++r) xres[s][n][r] = b2f(cur[s][qq * 4 + r][n * 16 + m]);

  const f32x4 z4 = {0.f, 0.f, 0.f, 0.f};
  const int hselA = (qq < 2) ? 16 : 0;               // head stride for A-frag
  const int aoffA = (qq < 2) ? ((qq & 1) * 8) : 64;  // qq>=2 -> zero cols
  const int boff = (qq & 1) * 8;  // B-frag k>=16 multiplied by A zeros

#pragma unroll 1
  for (int l = 0; l < L_; ++l) {
    const short* TQ = wp + OFF_TQ + l * 4096;
    const short* TK = wp + OFF_TK + l * 4096;
    const short* TV = wp + OFF_TV + l * 4096;
    const short* TWO = wp + OFF_TWO + l * 4096;
    const short* TW1 = wp + OFF_TW1 + l * 4096;
    const short* TW2 = wp + OFF_TW2 + l * 4096;

    // phase 1: x A-frags to regs (x in LDS dead afterwards)
    bf16x8 ax0[2], ax1[2];
#pragma unroll
    for (int s = 0; s < 2; ++s) {
      ax0[s] = *(const bf16x8*)&cur[s][m][qq * 8];
      ax1[s] = *(const bf16x8*)&cur[s][m][32 + qq * 8];
    }
    SCHED_FENCE();

    // phase 2a-Q: q -> cur (over x); runtime h-loop (code-size)
#pragma unroll 1
    for (int h = 0; h < 4; ++h) {
      const int bn = (h * 16 + m) * 64 + qq * 8;
      bf16x8 bq0 = *(const bf16x8*)(TQ + bn), bq1 = *(const bf16x8*)(TQ + bn + 32);
#pragma unroll
      for (int s = 0; s < 2; ++s) {
        f32x4 qa = MFMA(ax0[s], bq0, z4); qa = MFMA(ax1[s], bq1, qa);
#pragma unroll
        for (int r = 0; r < 4; ++r) cur[s][qq * 4 + r][h * 16 + m] = b16_ru(qa[r]);
      }
    }
    SCHED_FENCE();

    // phase 2a-K: k -> oth
#pragma unroll 1
    for (int h = 0; h < 4; ++h) {
      const int bn = (h * 16 + m) * 64 + qq * 8;
      bf16x8 bk0 = *(const bf16x8*)(TK + bn), bk1 = *(const bf16x8*)(TK + bn + 32);
#pragma unroll
      for (int s = 0; s < 2; ++s) {
        f32x4 ka = MFMA(ax0[s], bk0, z4); ka = MFMA(ax1[s], bk1, ka);
#pragma unroll
        for (int r = 0; r < 4; ++r) oth[s][qq * 4 + r][h * 16 + m] = b16_ru(ka[r]);
      }
    }
    SCHED_FENCE();

    // phase 3+4 fused per head: S_h = q k^T, p = exp(S/4) -> cur (over q[h];
    // reads of q[h]/k[h] precede the p[h] write in-order on the DS pipe)
#pragma unroll 1
    for (int h = 0; h < 4; ++h) {
#pragma unroll
      for (int s = 0; s < 2; ++s) {
        bf16x8 aq = *(const bf16x8*)&cur[s][m][h * hselA + aoffA];
        bf16x8 bk = *(const bf16x8*)&oth[s][m][h * 16 + boff];
        f32x4 sc = MFMA(aq, bk, z4);
#pragma unroll
        for (int r = 0; r < 4; ++r) {
          float e = __expf(sc[r] * 0.25f);
          cur[s][qq * 4 + r][h * 16 + m] = b16_ru(e);
        }
      }
    }
    SCHED_FENCE();

    // phase 2b: V -> vT into oth (over k; all k reads done above)
#pragma unroll 1
    for (int h = 0; h < 4; ++h) {
      const int bn = (h * 16 + m) * 64 + qq * 8;
      bf16x8 bv0 = *(const bf16x8*)(TV + bn), bv1 = *(const bf16x8*)(TV + bn + 32);
#pragma unroll
      for (int s = 0; s < 2; ++s) {
        f32x4 va = MFMA(ax0[s], bv0, z4); va = MFMA(ax1[s], bv1, va);
        // vT[kd][h*16+t]: 4 consecutive t in-lane -> one b64
        *(uint2*)&oth[s][m][h * 16 + qq * 4] =
            make_uint2(pack2_ru(va[0], va[1]), pack2_ru(va[2], va[3]));
      }
    }
    SCHED_FENCE();

    // phase 5+6 fused per head: O_h = p V (rowsum via ones-B MFMA), normalize,
    // concat -> cur (over p[h]; p[h] reads precede the o[h] write in-order)
    {
      const short s1b = (short)0x3F80;
      const bf16x8 ones8 = {s1b, s1b, s1b, s1b, s1b, s1b, s1b, s1b};
#pragma unroll 1
      for (int h = 0; h < 4; ++h) {
#pragma unroll
        for (int s = 0; s < 2; ++s) {
          bf16x8 ap = *(const bf16x8*)&cur[s][m][h * hselA + aoffA];
          bf16x8 bv = *(const bf16x8*)&oth[s][m][h * 16 + boff];
          f32x4 ot = MFMA(ap, bv, z4);
          f32x4 rs = MFMA(ap, ones8, z4);
#pragma unroll
          for (int r = 0; r < 4; ++r) {
            float o = ot[r] * __builtin_amdgcn_rcpf(rs[r]);
            cur[s][qq * 4 + r][h * 16 + m] = b16_ru(o);
          }
        }
      }
    }
    SCHED_FENCE();

    // phase 7: x1 = LN1(x + o@Wo + bo) -> oth (over vT), xres in place
    // (n stays unrolled: xres is compile-time indexed)
    {
      bf16x8 ao0[2], ao1[2];
#pragma unroll
      for (int s = 0; s < 2; ++s) {
        ao0[s] = *(const bf16x8*)&cur[s][m][qq * 8];
        ao1[s] = *(const bf16x8*)&cur[s][m][32 + qq * 8];
      }
#pragma unroll
      for (int n = 0; n < 4; ++n) {
        const int bn = (n * 16 + m) * 64 + qq * 8;
        bf16x8 w0 = *(const bf16x8*)(TWO + bn), w1 = *(const bf16x8*)(TWO + bn + 32);
        float bcol = bo[l * E_ + n * 16 + m];
#pragma unroll
        for (int s = 0; s < 2; ++s) {
          f32x4 d = MFMA(ao0[s], w0, z4); d = MFMA(ao1[s], w1, d);
#pragma unroll
          for (int r = 0; r < 4; ++r) xres[s][n][r] += d[r] + bcol;
        }
      }
#pragma unroll
      for (int s = 0; s < 2; ++s) ln16(xres[s]);
#pragma unroll
      for (int n = 0; n < 4; ++n) {
        float g = ln1g[l * E_ + n * 16 + m];
        float bb = ln1b[l * E_ + n * 16 + m];
#pragma unroll
        for (int s = 0; s < 2; ++s)
#pragma unroll
          for (int r = 0; r < 4; ++r) {
            float xv = fmaf(xres[s][n][r], g, bb);
            xres[s][n][r] = xv;
            oth[s][qq * 4 + r][n * 16 + m] = b16_ru(xv);
          }
      }
    }
    SCHED_FENCE();

    // phase 8: h1 = relu(x1@W1 + b1) -> cur (over ob); runtime n-loop
    {
      bf16x8 a10[2], a11[2];
#pragma unroll
      for (int s = 0; s < 2; ++s) {
        a10[s] = *(const bf16x8*)&oth[s][m][qq * 8];
        a11[s] = *(const bf16x8*)&oth[s][m][32 + qq * 8];
      }
#pragma unroll 1
      for (int n = 0; n < 4; ++n) {
        const int bn = (n * 16 + m) * 64 + qq * 8;
        bf16x8 w0 = *(const bf16x8*)(TW1 + bn), w1 = *(const bf16x8*)(TW1 + bn + 32);
        float bcol = b1[l * E_ + n * 16 + m];
#pragma unroll
        for (int s = 0; s < 2; ++s) {
          f32x4 acc = MFMA(a10[s], w0, z4); acc = MFMA(a11[s], w1, acc);
#pragma unroll
          for (int r = 0; r < 4; ++r) {
            float hv = fmaxf(acc[r] + bcol, 0.f);
            cur[s][qq * 4 + r][n * 16 + m] = b16_ru(hv);
          }
        }
      }
    }
    SCHED_FENCE();

    // phase 9: x = LN2(x1 + h1@W2 + b2) -> oth (over x1), xres in place
    {
      bf16x8 a20[2], a21[2];
#pragma unroll
      for (int s = 0; s < 2; ++s) {
        a20[s] = *(const bf16x8*)&cur[s][m][qq * 8];
        a21[s] = *(const bf16x8*)&cur[s][m][32 + qq * 8];
      }
#pragma unroll
      for (int n = 0; n < 4; ++n) {
        const int bn = (n * 16 + m) * 64 + qq * 8;
        bf16x8 w0 = *(const bf16x8*)(TW2 + bn), w1 = *(const bf16x8*)(TW2 + bn + 32);
        float bcol = b2[l * E_ + n * 16 + m];
#pragma unroll
        for (int s = 0; s < 2; ++s) {
          f32x4 d = MFMA(a20[s], w0, z4); d = MFMA(a21[s], w1, d);
#pragma unroll
          for (int r = 0; r < 4; ++r) xres[s][n][r] += d[r] + bcol;
        }
      }
#pragma unroll
      for (int s = 0; s < 2; ++s) ln16(xres[s]);
#pragma unroll
      for (int n = 0; n < 4; ++n) {
        float g = ln2g[l * E_ + n * 16 + m];
        float bb = ln2b[l * E_ + n * 16 + m];
#pragma unroll
        for (int s = 0; s < 2; ++s)
#pragma unroll
          for (int r = 0; r < 4; ++r) {
            float xv = fmaf(xres[s][n][r], g, bb);
            xres[s][n][r] = xv;
            oth[s][qq * 4 + r][n * 16 + m] = b16_ru(xv);
          }
      }
    }
    SCHED_FENCE();

    // ping-pong arenas: next layer's x is in oth
#pragma unroll
    for (int s = 0; s < 2; ++s) {
      short(*tmp)[72] = cur[s]; cur[s] = oth[s]; oth[s] = tmp;
    }
  }

  // epilogue: logits = x @ Wout + bout; runtime n-loop (6 n-tiles)
  {
    bf16x8 af0[2], af1[2];
#pragma unroll
    for (int s = 0; s < 2; ++s) {
      af0[s] = *(const bf16x8*)&cur[s][m][qq * 8];
      af1[s] = *(const bf16x8*)&cur[s][m][32 + qq * 8];
    }
    const short* TWOUT = wp + OFF_TWOUT;
#pragma unroll 1
    for (int n = 0; n < 6; ++n) {
      const int bn = (n * 16 + m) * 64 + qq * 8;
      bf16x8 w0 = *(const bf16x8*)(TWOUT + bn), w1 = *(const bf16x8*)(TWOUT + bn + 32);
      float bcol = bout[n * 16 + m];
#pragma unroll
      for (int s = 0; s < 2; ++s) {
        f32x4 acc = MFMA(af0[s], w0, z4); acc = MFMA(af1[s], w1, acc);
#pragma unroll
        for (int r = 0; r < 4; ++r)
          out[((seq0 + s) * T_ + qq * 4 + r) * V_ + n * 16 + m] = acc[r] + bcol;
      }
    }
  }
}

extern "C" void kernel_launch(void* const* d_in, const int* in_sizes, int n_in,
                              void* d_out, int out_size, void* d_ws, size_t ws_size,
                              hipStream_t stream) {
  const int*   data    = (const int*)d_in[0];
  const float* tok_emb = (const float*)d_in[1];
  const float* pos_emb = (const float*)d_in[2];
  const float* Wq      = (const float*)d_in[3];
  const float* Wk      = (const float*)d_in[4];
  const float* Wv      = (const float*)d_in[5];
  const float* Wo      = (const float*)d_in[6];
  const float* bo      = (const float*)d_in[7];
  const float* ln1g    = (const float*)d_in[8];
  const float* ln1b    = (const float*)d_in[9];
  const float* ln2g    = (const float*)d_in[10];
  const float* ln2b    = (const float*)d_in[11];
  const float* W1      = (const float*)d_in[12];
  const float* b1      = (const float*)d_in[13];
  const float* W2      = (const float*)d_in[14];
  const float* b2      = (const float*)d_in[15];
  const float* Wout    = (const float*)d_in[16];
  const float* bout    = (const float*)d_in[17];
  float* out = (float*)d_out;
  short* wp = (short*)d_ws;  // 104448*2 = 208896 B of workspace

  prep_weights<<<(PREP_TOT + 255) / 256, 256, 0, stream>>>(
      Wq, Wk, Wv, Wo, W1, W2, Wout, wp);

  const int B = in_sizes[0] / T_;  // 16384 sequences, 8 per block (2 per wave)
  bert_mfma<<<B / 8, 256, 0, stream>>>(data, tok_emb, pos_emb, bo, ln1g, ln1b,
                                       ln2g, ln2b, b1, b2, bout, wp, out);
}

// Round 12
// 348.838 us; speedup vs baseline: 1.5948x; 1.1681x over previous
//
#include <hip/hip_runtime.h>

#define T_ 16
#define E_ 64
#define V_ 96
#define L_ 4

typedef unsigned int u32;
typedef unsigned short u16;
typedef __attribute__((ext_vector_type(8))) short bf16x8;
typedef __attribute__((ext_vector_type(4))) float f32x4;

#define MFMA(a, b, c) __builtin_amdgcn_mfma_f32_16x16x32_bf16(a, b, c, 0, 0, 0)
#define SCHED_FENCE() __builtin_amdgcn_sched_barrier(0)

// ws layout (bf16/short elements): [n][k] per matrix — read as B-frag (col=n,
// K=k) OR as A-frag (row=n, K=k); both use identical per-lane addressing.
#define OFF_TQ 0
#define OFF_TK 16384
#define OFF_TV 32768
#define OFF_TWO 49152
#define OFF_TW1 65536
#define OFF_TW2 81920
#define OFF_TWOUT 98304
#define PREP_TOT 104448

__device__ __forceinline__ short f2b_rne(float f) {  // fp32 -> bf16 RNE (prep only)
  u32 u = __float_as_uint(f);
  u32 r = (u + 0x7fffu + ((u >> 16) & 1u)) >> 16;
  return (short)r;
}
__device__ __forceinline__ float b2f(short s) {
  return __uint_as_float(((u32)(u16)s) << 16);
}
// round-half-up bf16 pack: low short = bf16(a), high short = bf16(b). 3 VALU.
__device__ __forceinline__ u32 pack2_ru(float a, float b) {
  return __builtin_amdgcn_perm(__float_as_uint(a) + 0x8000u,
                               __float_as_uint(b) + 0x8000u, 0x03020706u);
}
// f32x4 C-regs -> bf16x8 frag {v0,v1,v2,v3, 0,0,0,0}: reinterprets a C-layout
// result as an A/B fragment with upper-K zeroed. Because BOTH operands of the
// downstream MFMA use the same slot->index mapping, the K permutation cancels
// and the zero slots contribute nothing.
__device__ __forceinline__ bf16x8 pk4z(f32x4 a) {
  union { bf16x8 v; u32 w[4]; } u;
  u.w[0] = pack2_ru(a[0], a[1]);
  u.w[1] = pack2_ru(a[2], a[3]);
  u.w[2] = 0u;
  u.w[3] = 0u;
  return u.v;
}

__global__ void __launch_bounds__(256) prep_weights(
    const float* __restrict__ Wq, const float* __restrict__ Wk,
    const float* __restrict__ Wv, const float* __restrict__ Wo,
    const float* __restrict__ W1, const float* __restrict__ W2,
    const float* __restrict__ Wout, short* __restrict__ wpo) {
  int id = blockIdx.x * 256 + threadIdx.x;
  if (id >= PREP_TOT) return;
  float v;
  if (id < OFF_TWO) {                       // TQ/TK/TV: n = h*16+kq, k = e
    int which = id >> 14;                   // 0=Q,1=K,2=V
    int r = id & 16383;
    int l = r >> 12, n = (r >> 6) & 63, e = r & 63;
    int h = n >> 4, kq = n & 15;
    const float* W = which == 0 ? Wq : (which == 1 ? Wk : Wv);
    v = W[((l * 4 + h) * 64 + e) * 16 + kq];
  } else if (id < OFF_TWOUT) {              // TWo/TW1/TW2: n = out col, k = e
    int id2 = id - OFF_TWO;
    int which = id2 >> 14;                  // 0=Wo,1=W1,2=W2
    int r = id2 & 16383;
    int l = r >> 12, n = (r >> 6) & 63, e = r & 63;
    const float* W = which == 0 ? Wo : (which == 1 ? W1 : W2);
    v = W[(l * 64 + e) * 64 + n];
  } else {                                  // TWout: n = vocab col, k = e
    int r = id - OFF_TWOUT;
    int n = r >> 6, e = r & 63;
    v = Wout[e * 96 + n];
  }
  wpo[id] = f2b_rne(v);
}

// LayerNorm over 64 e-values of ONE token held per lane as vals[4 tiles][4 r]
// (e = 16*T + 4*qq + r). In-lane sum of 16 + cross-qq via shfl_xor 16/32.
__device__ __forceinline__ void ln64(float vals[4][4]) {
  float sm = 0.f;
#pragma unroll
  for (int t = 0; t < 4; ++t)
#pragma unroll
    for (int r = 0; r < 4; ++r) sm += vals[t][r];
  sm += __shfl_xor(sm, 16); sm += __shfl_xor(sm, 32);
  float mean = sm * 0.015625f;
  float s2 = 0.f;
#pragma unroll
  for (int t = 0; t < 4; ++t)
#pragma unroll
    for (int r = 0; r < 4; ++r) { float d = vals[t][r] - mean; s2 = fmaf(d, d, s2); }
  s2 += __shfl_xor(s2, 16); s2 += __shfl_xor(s2, 32);
  float rst = rsqrtf(s2 * 0.015625f + 1e-5f);
#pragma unroll
  for (int t = 0; t < 4; ++t)
#pragma unroll
    for (int r = 0; r < 4; ++r) vals[t][r] = (vals[t][r] - mean) * rst;
}

// TRANSPOSE-FREE restructure (r11, resubmitted r12 after infra failure).
// Principle: feeding a matrix's C-layout registers (lane=col, regs=rows
// 4qq+r) as an A/B-fragment presents it TRANSPOSED to the MFMA
// (value (qq,i) -> K-slot qq*8+i; same permutation on both operands, so it
// cancels; zero upper slots contribute nothing). So:
//   qT = mfma(A=TQ, B=x)   (D[kq][t], lane=t)     — same prep bytes/addrs
//   kT = mfma(A=TK, B=x);  v = mfma(A=x, B=TV)    (D[t][kd], lane=kd)
//   S^T = mfma(kT-regs, qT-regs)  — REGISTERS ONLY (K=16 real + zero pad)
//   p = exp(S^T/…) in regs; O^T = mfma(v-regs, p-regs); rowsum = mfma(ones,p)
//   (rowsum is the FULL 16-key sum: the MFMA K-sum gathers across qq groups)
// The whole attention block has ZERO LDS round trips. FF flips to transposed
// outputs (x1^T/h1^T/x^T, lane=token): C rows are then 4 CONSECUTIVE e-cols,
// so every LDS store is pack2+ds_write_b64 (3 ops vs 8 b16 scatter ops), and
// every read stays ds_read_b128 row-major. LN per-token in-lane + shfl 16/32.
// ONE arena per seq (x -> o -> x1 -> h1 -> x overwrite with hoisted reads; DS
// pipe in-order per wave, LDS wave-private, no __syncthreads).
__global__ void __launch_bounds__(256, 3) bert_mfma(
    const int* __restrict__ data,
    const float* __restrict__ tok_emb, const float* __restrict__ pos_emb,
    const float* __restrict__ bo, const float* __restrict__ ln1g,
    const float* __restrict__ ln1b, const float* __restrict__ ln2g,
    const float* __restrict__ ln2b, const float* __restrict__ b1,
    const float* __restrict__ b2, const float* __restrict__ bout,
    const short* __restrict__ wp, float* __restrict__ out) {
  __shared__ __align__(16) short R[4][2][16][72];  // [wave][seq] single arena

  const int w = threadIdx.x >> 6;
  const int lane = threadIdx.x & 63;
  const int m = lane & 15;   // token column of transposed outputs / frag row
  const int qq = lane >> 4;  // K-chunk / C-row group
  const int seq0 = blockIdx.x * 8 + w * 2;

  short(*ar[2])[72] = {R[w][0], R[w][1]};

  // ---- embedding: x = tok_emb[data] + pos_emb -> ar[s] bf16 [t][e] ----
#pragma unroll
  for (int s = 0; s < 2; ++s) {
    const int t = lane >> 2;
    const int c0 = (lane & 3) * 16;
    const int tok = data[(seq0 + s) * T_ + t];
    const float4* tp = (const float4*)(tok_emb + tok * E_ + c0);
    const float4* pp = (const float4*)(pos_emb + t * E_ + c0);
    u32 buf[8];
#pragma unroll
    for (int q = 0; q < 4; ++q) {
      float4 a = tp[q], b = pp[q];
      buf[q * 2 + 0] = pack2_ru(a.x + b.x, a.y + b.y);
      buf[q * 2 + 1] = pack2_ru(a.z + b.z, a.w + b.w);
    }
    ((bf16x8*)&ar[s][t][c0])[0] = ((bf16x8*)buf)[0];
    *(bf16x8*)&ar[s][t][c0 + 8] = ((bf16x8*)(buf + 4))[0];
  }

  // residual stream (transposed layout): xres[s][T][r] = x[t=m][e=16T+4qq+r]
  float xres[2][4][4];
#pragma unroll
  for (int s = 0; s < 2; ++s)
#pragma unroll
    for (int t = 0; t < 4; ++t) {
      uint2 du = *(uint2*)&ar[s][m][t * 16 + qq * 4];
      xres[s][t][0] = b2f((short)(du.x & 0xffffu));
      xres[s][t][1] = b2f((short)(du.x >> 16));
      xres[s][t][2] = b2f((short)(du.y & 0xffffu));
      xres[s][t][3] = b2f((short)(du.y >> 16));
    }

  const short s1b = (short)0x3F80;
  const bf16x8 ones8 = {s1b, s1b, s1b, s1b, s1b, s1b, s1b, s1b};
  const f32x4 z4 = {0.f, 0.f, 0.f, 0.f};

#pragma unroll 1
  for (int l = 0; l < L_; ++l) {
    const short* TQ = wp + OFF_TQ + l * 4096;
    const short* TK = wp + OFF_TK + l * 4096;
    const short* TV = wp + OFF_TV + l * 4096;
    const short* TWO = wp + OFF_TWO + l * 4096;
    const short* TW1 = wp + OFF_TW1 + l * 4096;
    const short* TW2 = wp + OFF_TW2 + l * 4096;

    // x fragments to regs (serve as both A- and B-frags; x LDS dead after)
    bf16x8 ax0[2], ax1[2];
#pragma unroll
    for (int s = 0; s < 2; ++s) {
      ax0[s] = *(const bf16x8*)&ar[s][m][qq * 8];
      ax1[s] = *(const bf16x8*)&ar[s][m][32 + qq * 8];
    }
    SCHED_FENCE();

    // ---- attention, fully in registers per head; o -> arena (over x) ----
#pragma unroll 1
    for (int h = 0; h < 4; ++h) {
      const int bn = (h * 16 + m) * 64 + qq * 8;
      bf16x8 wq0 = *(const bf16x8*)(TQ + bn), wq1 = *(const bf16x8*)(TQ + bn + 32);
      bf16x8 wk0 = *(const bf16x8*)(TK + bn), wk1 = *(const bf16x8*)(TK + bn + 32);
      bf16x8 wv0 = *(const bf16x8*)(TV + bn), wv1 = *(const bf16x8*)(TV + bn + 32);
#pragma unroll
      for (int s = 0; s < 2; ++s) {
        // qT[kq][t], kT[kq][t] (lane=t); v[t][kd] (lane=kd)
        f32x4 qT = MFMA(wq0, ax0[s], z4); qT = MFMA(wq1, ax1[s], qT);
        f32x4 kT = MFMA(wk0, ax0[s], z4); kT = MFMA(wk1, ax1[s], kT);
        f32x4 vv = MFMA(ax0[s], wv0, z4); vv = MFMA(ax1[s], wv1, vv);
        bf16x8 qpk = pk4z(qT), kpk = pk4z(kT), vpk = pk4z(vv);
        // S^T[s'][t] = sum_kq k[s'][kq] q[t][kq]  (K=16 real, upper zeros)
        f32x4 sT = MFMA(kpk, qpk, z4);
        f32x4 ev;
#pragma unroll
        for (int r = 0; r < 4; ++r) ev[r] = __expf(sT[r] * 0.25f);
        bf16x8 ppk = pk4z(ev);
        // O^T[kd][t] = sum_s v[s][kd] p[t][s];  rowsum via ones-A MFMA
        f32x4 oT = MFMA(vpk, ppk, z4);
        f32x4 rs = MFMA(ones8, ppk, z4);
        float inv = __builtin_amdgcn_rcpf(rs[0]);
        // o row-major [t][h*16+kd]: lane t=m writes kd=4qq..4qq+3 -> one b64
        *(uint2*)&ar[s][m][h * 16 + qq * 4] =
            make_uint2(pack2_ru(oT[0] * inv, oT[1] * inv),
                       pack2_ru(oT[2] * inv, oT[3] * inv));
      }
    }
    SCHED_FENCE();

    // ---- phase 7: x1 = LN1(x + o@Wo + bo); transposed accumulate ----
    {
      bf16x8 ao0[2], ao1[2];
#pragma unroll
      for (int s = 0; s < 2; ++s) {
        ao0[s] = *(const bf16x8*)&ar[s][m][qq * 8];
        ao1[s] = *(const bf16x8*)&ar[s][m][32 + qq * 8];
      }
#pragma unroll
      for (int t = 0; t < 4; ++t) {
        const int bn = (t * 16 + m) * 64 + qq * 8;
        bf16x8 w0 = *(const bf16x8*)(TWO + bn), w1 = *(const bf16x8*)(TWO + bn + 32);
        float4 bc = *(const float4*)(bo + l * E_ + t * 16 + qq * 4);
#pragma unroll
        for (int s = 0; s < 2; ++s) {
          f32x4 d = MFMA(w0, ao0[s], z4); d = MFMA(w1, ao1[s], d);
          xres[s][t][0] += d[0] + bc.x; xres[s][t][1] += d[1] + bc.y;
          xres[s][t][2] += d[2] + bc.z; xres[s][t][3] += d[3] + bc.w;
        }
      }
#pragma unroll
      for (int s = 0; s < 2; ++s) ln64(xres[s]);
#pragma unroll
      for (int t = 0; t < 4; ++t) {
        float4 g4 = *(const float4*)(ln1g + l * E_ + t * 16 + qq * 4);
        float4 b4 = *(const float4*)(ln1b + l * E_ + t * 16 + qq * 4);
#pragma unroll
        for (int s = 0; s < 2; ++s) {
          float x0 = fmaf(xres[s][t][0], g4.x, b4.x);
          float x1v = fmaf(xres[s][t][1], g4.y, b4.y);
          float x2 = fmaf(xres[s][t][2], g4.z, b4.z);
          float x3 = fmaf(xres[s][t][3], g4.w, b4.w);
          xres[s][t][0] = x0; xres[s][t][1] = x1v;
          xres[s][t][2] = x2; xres[s][t][3] = x3;
          *(uint2*)&ar[s][m][t * 16 + qq * 4] =
              make_uint2(pack2_ru(x0, x1v), pack2_ru(x2, x3));
        }
      }
    }
    SCHED_FENCE();

    // ---- phase 8: h1 = relu(x1@W1 + b1) -> arena (over x1) ----
    {
      bf16x8 a10[2], a11[2];
#pragma unroll
      for (int s = 0; s < 2; ++s) {
        a10[s] = *(const bf16x8*)&ar[s][m][qq * 8];
        a11[s] = *(const bf16x8*)&ar[s][m][32 + qq * 8];
      }
#pragma unroll 1
      for (int t = 0; t < 4; ++t) {
        const int bn = (t * 16 + m) * 64 + qq * 8;
        bf16x8 w0 = *(const bf16x8*)(TW1 + bn), w1 = *(const bf16x8*)(TW1 + bn + 32);
        float4 bc = *(const float4*)(b1 + l * E_ + t * 16 + qq * 4);
#pragma unroll
        for (int s = 0; s < 2; ++s) {
          f32x4 acc = MFMA(w0, a10[s], z4); acc = MFMA(w1, a11[s], acc);
          float h0 = fmaxf(acc[0] + bc.x, 0.f), h1v = fmaxf(acc[1] + bc.y, 0.f);
          float h2 = fmaxf(acc[2] + bc.z, 0.f), h3 = fmaxf(acc[3] + bc.w, 0.f);
          *(uint2*)&ar[s][m][t * 16 + qq * 4] =
              make_uint2(pack2_ru(h0, h1v), pack2_ru(h2, h3));
        }
      }
    }
    SCHED_FENCE();

    // ---- phase 9: x = LN2(x1 + h1@W2 + b2) -> arena (over h1) ----
    {
      bf16x8 a20[2], a21[2];
#pragma unroll
      for (int s = 0; s < 2; ++s) {
        a20[s] = *(const bf16x8*)&ar[s][m][qq * 8];
        a21[s] = *(const bf16x8*)&ar[s][m][32 + qq * 8];
      }
#pragma unroll
      for (int t = 0; t < 4; ++t) {
        const int bn = (t * 16 + m) * 64 + qq * 8;
        bf16x8 w0 = *(const bf16x8*)(TW2 + bn), w1 = *(const bf16x8*)(TW2 + bn + 32);
        float4 bc = *(const float4*)(b2 + l * E_ + t * 16 + qq * 4);
#pragma unroll
        for (int s = 0; s < 2; ++s) {
          f32x4 d = MFMA(w0, a20[s], z4); d = MFMA(w1, a21[s], d);
          xres[s][t][0] += d[0] + bc.x; xres[s][t][1] += d[1] + bc.y;
          xres[s][t][2] += d[2] + bc.z; xres[s][t][3] += d[3] + bc.w;
        }
      }
#pragma unroll
      for (int s = 0; s < 2; ++s) ln64(xres[s]);
#pragma unroll
      for (int t = 0; t < 4; ++t) {
        float4 g4 = *(const float4*)(ln2g + l * E_ + t * 16 + qq * 4);
        float4 b4 = *(const float4*)(ln2b + l * E_ + t * 16 + qq * 4);
#pragma unroll
        for (int s = 0; s < 2; ++s) {
          float x0 = fmaf(xres[s][t][0], g4.x, b4.x);
          float x1v = fmaf(xres[s][t][1], g4.y, b4.y);
          float x2 = fmaf(xres[s][t][2], g4.z, b4.z);
          float x3 = fmaf(xres[s][t][3], g4.w, b4.w);
          xres[s][t][0] = x0; xres[s][t][1] = x1v;
          xres[s][t][2] = x2; xres[s][t][3] = x3;
          *(uint2*)&ar[s][m][t * 16 + qq * 4] =
              make_uint2(pack2_ru(x0, x1v), pack2_ru(x2, x3));
        }
      }
    }
    SCHED_FENCE();
  }

  // ---- epilogue: logits^T tiles = mfma(A=TWOUT, B=x); float4 stores ----
  {
    bf16x8 af0[2], af1[2];
#pragma unroll
    for (int s = 0; s < 2; ++s) {
      af0[s] = *(const bf16x8*)&ar[s][m][qq * 8];
      af1[s] = *(const bf16x8*)&ar[s][m][32 + qq * 8];
    }
    const short* TWOUT = wp + OFF_TWOUT;
#pragma unroll 1
    for (int t = 0; t < 6; ++t) {
      const int bn = (t * 16 + m) * 64 + qq * 8;
      bf16x8 w0 = *(const bf16x8*)(TWOUT + bn), w1 = *(const bf16x8*)(TWOUT + bn + 32);
      float4 bc = *(const float4*)(bout + t * 16 + qq * 4);
#pragma unroll
      for (int s = 0; s < 2; ++s) {
        f32x4 acc = MFMA(w0, af0[s], z4); acc = MFMA(w1, af1[s], acc);
        float4 o4 = make_float4(acc[0] + bc.x, acc[1] + bc.y,
                                acc[2] + bc.z, acc[3] + bc.w);
        *(float4*)&out[((seq0 + s) * T_ + m) * V_ + t * 16 + qq * 4] = o4;
      }
    }
  }
}

extern "C" void kernel_launch(void* const* d_in, const int* in_sizes, int n_in,
                              void* d_out, int out_size, void* d_ws, size_t ws_size,
                              hipStream_t stream) {
  const int*   data    = (const int*)d_in[0];
  const float* tok_emb = (const float*)d_in[1];
  const float* pos_emb = (const float*)d_in[2];
  const float* Wq      = (const float*)d_in[3];
  const float* Wk      = (const float*)d_in[4];
  const float* Wv      = (const float*)d_in[5];
  const float* Wo      = (const float*)d_in[6];
  const float* bo      = (const float*)d_in[7];
  const float* ln1g    = (const float*)d_in[8];
  const float* ln1b    = (const float*)d_in[9];
  const float* ln2g    = (const float*)d_in[10];
  const float* ln2b    = (const float*)d_in[11];
  const float* W1      = (const float*)d_in[12];
  const float* b1      = (const float*)d_in[13];
  const float* W2      = (const float*)d_in[14];
  const float* b2      = (const float*)d_in[15];
  const float* Wout    = (const float*)d_in[16];
  const float* bout    = (const float*)d_in[17];
  float* out = (float*)d_out;
  short* wp = (short*)d_ws;  // 104448*2 = 208896 B of workspace

  prep_weights<<<(PREP_TOT + 255) / 256, 256, 0, stream>>>(
      Wq, Wk, Wv, Wo, W1, W2, Wout, wp);

  const int B = in_sizes[0] / T_;  // 16384 sequences, 8 per block (2 per wave)
  bert_mfma<<<B / 8, 256, 0, stream>>>(data, tok_emb, pos_emb, bo, ln1g, ln1b,
                                       ln2g, ln2b, b1, b2, bout, wp, out);
}